// Round 4
// baseline (839.450 us; speedup 1.0000x reference)
//
#include <hip/hip_runtime.h>
#include <math.h>

#define BB 8
#define NN 1024
#define MM 256
#define BETA 8
#define M1 16
#define NFEAT 64
#define HH 128
#define NTOT 1088   /* N + NGHOST */
#define F3 (NTOT*3) /* 3264 */
#define RMINf 0.5f
#define SPANf 5.5f
#define PIf 3.14159265358979323846f

#define OUT_EI 8
#define OUT_FORCE 8200          /* 8 + 8192 */
#define OUT_VIR 34312           /* 8200 + 8*1088*3 */

#define NGROUP 32               /* scatter groups per batch */
#define PAIRS_PER_BATCH (NN*MM) /* 262144 */
#define PAIRS_PER_GROUP (PAIRS_PER_BATCH/NGROUP) /* 8192 */

#define MT 16                   /* atoms per MLP tile */
#define PAD 18                  /* activation LDS leading-dim pad (b64-aligned) */

/* workspace float offsets */
#define WS_S     0
#define WS_DF    (WS_S + 8192*64)
#define WS_DX    (WS_DF + 8192*64)
#define WS_DY    (WS_DX + 8192*256)
#define WS_DZ    (WS_DY + 8192*256)
#define WS_STATP (WS_DZ + 8192*256)      /* 8192*2 */
#define WS_MUSTD (WS_STATP + 8192*2)     /* 4 */
#define WS_VIRP  (WS_MUSTD + 4)          /* 8192*9 */
#define WS_FPART (WS_VIRP + 8192*9)      /* 8*32*3264 */
#define WS_WT    (WS_FPART + BB*NGROUP*F3) /* 81920 */
#define WT0_OFF  0
#define WT1_OFF  16384
#define WT2_OFF  49152

__global__ __launch_bounds__(256) void k_transpose(
    const float* __restrict__ W0, const float* __restrict__ W1,
    const float* __restrict__ W2, float* __restrict__ wt)
{
  const int idx = blockIdx.x*256 + threadIdx.x;
  if (idx < 16384) {
    const int t = idx >> 13, rem = idx & 8191;
    const int j = rem >> 6, f = rem & 63;
    wt[WT0_OFF + idx] = W0[t*8192 + f*128 + j];
  } else if (idx < 49152) {
    const int i = idx - 16384;
    const int t = i >> 14, rem = i & 16383;
    const int j = rem >> 7, f = rem & 127;
    wt[WT1_OFF + i] = W1[t*16384 + f*128 + j];
  } else if (idx < 81920) {
    const int i = idx - 49152;
    const int t = i >> 14, rem = i & 16383;
    const int j = rem >> 7, f = rem & 127;
    wt[WT2_OFF + i] = W2[t*16384 + f*128 + j];
  }
}

/* ---- features via U-factorization: S[p][a] = (1/M) sum_tj sum_k c[tj][p][k] U[tj][k][a] ---- */
__global__ __launch_bounds__(256) void k_feat(
    const float* __restrict__ rvec, const int* __restrict__ tmap,
    const float* __restrict__ c_param, float* __restrict__ S_ws,
    float* __restrict__ statp)
{
  __shared__ float rv[768];
  __shared__ float c_lds[256];
  __shared__ float prod[256*33];
  __shared__ float part[8*32];
  __shared__ float U[2*32];
  __shared__ float S_lds[64];
  const int bn = blockIdx.x;
  const int n = bn & (NN-1);
  const int tid = threadIdx.x;
  const int ti = tmap[n];
  c_lds[tid] = c_param[ti*256 + tid];
  const float* rb = rvec + (size_t)bn*MM*3;
  rv[tid] = rb[tid]; rv[tid+256] = rb[tid+256]; rv[tid+512] = rb[tid+512];
  __syncthreads();
  const int m = tid;
  const float x = rv[3*m], y = rv[3*m+1], z = rv[3*m+2];
  const float r = sqrtf(x*x + y*y + z*z);
  const float inv_r = 1.0f / r;
  const float ux = x*inv_r, uy = y*inv_r, uz = z*inv_r;
  float u = 2.0f*(r - RMINf)/SPANf - 1.0f;
  u = fminf(fmaxf(u, -1.0f), 1.0f);
  const float fc = 0.5f*(__cosf(PIf*(r - RMINf)/SPANf) + 1.0f);
  float T[BETA];
  T[0] = 1.0f; T[1] = u;
  #pragma unroll
  for (int k = 2; k < BETA; ++k) T[k] = 2.0f*u*T[k-1] - T[k-2];
  float* pr = &prod[m*33];
  #pragma unroll
  for (int k = 0; k < BETA; ++k) {
    const float ft = fc*T[k];
    pr[k*4+0] = ft;
    pr[k*4+1] = ft*ux;
    pr[k*4+2] = ft*uy;
    pr[k*4+3] = ft*uz;
  }
  __syncthreads();
  {
    const int c = tid & 31, oct = tid >> 5;
    const int m0 = oct*32;
    float s = 0.f;
    #pragma unroll 8
    for (int i = 0; i < 32; ++i) s += prod[(m0+i)*33 + c];
    part[oct*32 + c] = s;
  }
  __syncthreads();
  if (tid < 64) {
    const int tj = tid >> 5, c = tid & 31;
    U[tid] = part[(tj*4+0)*32+c] + part[(tj*4+1)*32+c]
           + part[(tj*4+2)*32+c] + part[(tj*4+3)*32+c];
  }
  __syncthreads();
  if (tid < 64) {
    const int p = tid >> 2, a = tid & 3;
    float s = 0.f;
    #pragma unroll
    for (int tj = 0; tj < 2; ++tj)
      #pragma unroll
      for (int k = 0; k < 8; ++k)
        s += c_lds[tj*128 + p*8 + k] * U[tj*32 + k*4 + a];
    s *= (1.0f/(float)MM);
    S_lds[tid] = s;
    S_ws[(size_t)bn*64 + tid] = s;
  }
  __syncthreads();
  if (tid < 64) {
    const int p = tid >> 2, q = tid & 3;
    float f = 0.f;
    #pragma unroll
    for (int a = 0; a < 4; ++a) f += S_lds[p*4+a]*S_lds[q*4+a];
    float fs = f, fss = f*f;
    for (int o = 32; o > 0; o >>= 1) { fs += __shfl_down(fs, o); fss += __shfl_down(fss, o); }
    if (tid == 0) { statp[bn*2+0] = fs; statp[bn*2+1] = fss; }
  }
}

__global__ __launch_bounds__(1024) void k_stats(
    const int* __restrict__ tmap, const float* __restrict__ statp,
    float* __restrict__ mu_std)
{
  __shared__ float wred[16*5];
  const int tid = threadIdx.x;
  const int ti = tmap[tid];
  float fs = 0.f, fss = 0.f;
  for (int b = 0; b < BB; ++b) {
    fs  += statp[(b*NN + tid)*2 + 0];
    fss += statp[(b*NN + tid)*2 + 1];
  }
  float v[5];
  v[0] = (ti == 0) ? fs  : 0.f;
  v[1] = (ti == 0) ? fss : 0.f;
  v[2] = (ti == 1) ? fs  : 0.f;
  v[3] = (ti == 1) ? fss : 0.f;
  v[4] = (ti == 0) ? 1.f : 0.f;
  for (int o = 32; o > 0; o >>= 1)
    for (int i = 0; i < 5; ++i) v[i] += __shfl_down(v[i], o);
  if ((tid & 63) == 0)
    for (int i = 0; i < 5; ++i) wred[(tid >> 6)*5 + i] = v[i];
  __syncthreads();
  if (tid == 0) {
    float s[5] = {0,0,0,0,0};
    for (int w = 0; w < 16; ++w)
      for (int i = 0; i < 5; ++i) s[i] += wred[w*5 + i];
    const float c0 = s[4];
    for (int t = 0; t < 2; ++t) {
      const float cn = (t == 0) ? c0 : ((float)NN - c0);
      const float cnt = cn * (float)BB * (float)NFEAT;
      const float mu = s[t*2+0] / cnt;
      const float var = (s[t*2+1] - cnt*mu*mu) / (cnt - 1.0f);
      mu_std[t*2+0] = mu;
      mu_std[t*2+1] = sqrtf(fmaxf(var, 1e-20f));
    }
  }
}

/* ---- tiled MLP: 16 atoms/block, 2x4 register tile, activations in LDS ---- */
/* A layout: Abuf[k*PAD + atom] (wave-broadcast reads); B streamed 32x128 chunks */
#define GEMM128(WPTR, K, ABUF) \
  for (int kc = 0; kc < (K); kc += 32) { \
    __syncthreads(); \
    { const float4* _s = (const float4*)((WPTR) + kc*128); \
      float4* _d = (float4*)bb; \
      _d[tid] = _s[tid]; _d[tid+256] = _s[tid+256]; \
      _d[tid+512] = _s[tid+512]; _d[tid+768] = _s[tid+768]; } \
    __syncthreads(); \
    _Pragma("unroll") \
    for (int k = 0; k < 32; ++k) { \
      const float2 av = *(const float2*)&(ABUF)[(kc+k)*PAD + r0]; \
      const float4 bv = *(const float4*)&bb[k*128 + c0]; \
      acc[0][0] += av.x*bv.x; acc[0][1] += av.x*bv.y; acc[0][2] += av.x*bv.z; acc[0][3] += av.x*bv.w; \
      acc[1][0] += av.y*bv.x; acc[1][1] += av.y*bv.y; acc[1][2] += av.y*bv.z; acc[1][3] += av.y*bv.w; \
    } \
  }

__global__ __launch_bounds__(256) void k_mlp(
    const float* __restrict__ S_ws, const int* __restrict__ tmap,
    const float* __restrict__ mu_std, const float* __restrict__ wt,
    const float* __restrict__ W0, const float* __restrict__ b0,
    const float* __restrict__ W1, const float* __restrict__ b1,
    const float* __restrict__ W2, const float* __restrict__ b2,
    const float* __restrict__ Wout, const float* __restrict__ bout,
    float* __restrict__ dfeat_ws, float* __restrict__ out)
{
  __shared__ float xb[64*PAD];     /* normalized feat, k-major */
  __shared__ float t0b[128*PAD];   /* tanh(z0) */
  __shared__ float h1b[128*PAD];   /* t1 + t0 */
  __shared__ float dzb[128*PAD];   /* current backward dz (A operand) */
  __shared__ float bb[32*128];     /* weight chunk */
  __shared__ float sl[MT*64];
  __shared__ float es[MT];
  const int tb = blockIdx.x;
  const int bn0 = tb*MT;
  const int b = bn0 >> 10;
  const int tid = threadIdx.x;
  const int t = tmap[bn0 & (NN-1)];
  const int rg = tid >> 5, cg = tid & 31;
  const int r0 = rg*2;            /* 2 atoms per thread */
  const int c0 = cg*4;            /* 4 cols per thread */
  {
    const float4* src = (const float4*)(S_ws + (size_t)bn0*64);
    ((float4*)sl)[tid] = src[tid];
  }
  __syncthreads();
  const float mu = mu_std[t*2], sd = mu_std[t*2+1];
  const float inv_sd = 1.0f/sd;
  #pragma unroll
  for (int i = 0; i < 4; ++i) {
    const int e = i*256 + tid;
    const int r = e >> 6, f = e & 63;
    const int p = f >> 2, q = f & 3;
    const float* Sr = &sl[r*64];
    float s = 0.f;
    #pragma unroll
    for (int a = 0; a < 4; ++a) s += Sr[p*4+a]*Sr[q*4+a];
    xb[f*PAD + r] = (s - mu)*inv_sd;
  }

  float acc[2][4], dh1r[2][4], wor[4];

  /* L0: z0 = x @ W0 + b0, K=64 */
  {
    const float* bp = b0 + t*HH;
    const float bj0 = bp[c0], bj1 = bp[c0+1], bj2 = bp[c0+2], bj3 = bp[c0+3];
    #pragma unroll
    for (int i = 0; i < 2; ++i) { acc[i][0]=bj0; acc[i][1]=bj1; acc[i][2]=bj2; acc[i][3]=bj3; }
  }
  GEMM128(W0 + (size_t)t*NFEAT*HH, 64, xb);
  __syncthreads();
  #pragma unroll
  for (int i = 0; i < 2; ++i)
    #pragma unroll
    for (int j = 0; j < 4; ++j) t0b[(c0+j)*PAD + r0+i] = tanhf(acc[i][j]);

  /* L1: h1 = tanh(t0 @ W1 + b1) + t0 */
  {
    const float* bp = b1 + t*HH;
    const float bj0 = bp[c0], bj1 = bp[c0+1], bj2 = bp[c0+2], bj3 = bp[c0+3];
    #pragma unroll
    for (int i = 0; i < 2; ++i) { acc[i][0]=bj0; acc[i][1]=bj1; acc[i][2]=bj2; acc[i][3]=bj3; }
  }
  GEMM128(W1 + (size_t)t*HH*HH, 128, t0b);
  __syncthreads();
  #pragma unroll
  for (int i = 0; i < 2; ++i)
    #pragma unroll
    for (int j = 0; j < 4; ++j)
      h1b[(c0+j)*PAD + r0+i] = tanhf(acc[i][j]) + t0b[(c0+j)*PAD + r0+i];

  /* L2: z2 = h1 @ W2 + b2 */
  {
    const float* bp = b2 + t*HH;
    const float bj0 = bp[c0], bj1 = bp[c0+1], bj2 = bp[c0+2], bj3 = bp[c0+3];
    #pragma unroll
    for (int i = 0; i < 2; ++i) { acc[i][0]=bj0; acc[i][1]=bj1; acc[i][2]=bj2; acc[i][3]=bj3; }
  }
  GEMM128(W2 + (size_t)t*HH*HH, 128, h1b);
  __syncthreads();

  #pragma unroll
  for (int j = 0; j < 4; ++j) wor[j] = Wout[t*HH + c0 + j];

  /* energy + dz2 */
  {
    float pr0 = 0.f, pr1 = 0.f;
    #pragma unroll
    for (int i = 0; i < 2; ++i)
      #pragma unroll
      for (int j = 0; j < 4; ++j) {
        const float t2 = tanhf(acc[i][j]);
        const float h2 = t2 + h1b[(c0+j)*PAD + r0+i];
        if (i == 0) pr0 += h2*wor[j]; else pr1 += h2*wor[j];
        dzb[(c0+j)*PAD + r0+i] = wor[j]*(1.0f - t2*t2);
      }
    for (int o = 16; o > 0; o >>= 1) {
      pr0 += __shfl_down(pr0, o, 32);
      pr1 += __shfl_down(pr1, o, 32);
    }
    if (cg == 0) { es[r0] = pr0; es[r0+1] = pr1; }
  }
  __syncthreads();
  if (tid < MT) out[OUT_EI + bn0 + tid] = es[tid] + bout[t];
  if (tid == 0) {
    float s = 0.f;
    for (int i = 0; i < MT; ++i) s += es[i];
    atomicAdd(&out[b], s + (float)MT*bout[t]);
  }

  /* dh1 = wo + dz2 @ W2^T */
  #pragma unroll
  for (int i = 0; i < 2; ++i)
    #pragma unroll
    for (int j = 0; j < 4; ++j) acc[i][j] = wor[j];
  GEMM128(wt + WT2_OFF + (size_t)t*HH*HH, 128, dzb);
  #pragma unroll
  for (int i = 0; i < 2; ++i)
    #pragma unroll
    for (int j = 0; j < 4; ++j) dh1r[i][j] = acc[i][j];
  __syncthreads();
  /* dz1 = dh1 * (1 - t1^2), t1 = h1 - t0 */
  #pragma unroll
  for (int i = 0; i < 2; ++i)
    #pragma unroll
    for (int j = 0; j < 4; ++j) {
      const float t1 = h1b[(c0+j)*PAD + r0+i] - t0b[(c0+j)*PAD + r0+i];
      dzb[(c0+j)*PAD + r0+i] = dh1r[i][j]*(1.0f - t1*t1);
    }
  /* dh0 = dh1 + dz1 @ W1^T */
  #pragma unroll
  for (int i = 0; i < 2; ++i)
    #pragma unroll
    for (int j = 0; j < 4; ++j) acc[i][j] = dh1r[i][j];
  GEMM128(wt + WT1_OFF + (size_t)t*HH*HH, 128, dzb);
  __syncthreads();
  /* dz0 = dh0 * (1 - t0^2) */
  #pragma unroll
  for (int i = 0; i < 2; ++i)
    #pragma unroll
    for (int j = 0; j < 4; ++j) {
      const float t0 = t0b[(c0+j)*PAD + r0+i];
      dzb[(c0+j)*PAD + r0+i] = acc[i][j]*(1.0f - t0*t0);
    }
  /* dx = dz0 @ W0^T : MTx64 out; 2 atoms x 2 feats per thread */
  {
    float a2[2][2];
    a2[0][0]=0.f; a2[0][1]=0.f; a2[1][0]=0.f; a2[1][1]=0.f;
    const float* WT0t = wt + WT0_OFF + (size_t)t*HH*NFEAT;
    for (int kc = 0; kc < 128; kc += 32) {
      __syncthreads();
      { const float4* _s = (const float4*)(WT0t + kc*64);
        float4* _d = (float4*)bb;
        _d[tid] = _s[tid]; _d[tid+256] = _s[tid+256]; }
      __syncthreads();
      #pragma unroll
      for (int k = 0; k < 32; ++k) {
        const float2 av = *(const float2*)&dzb[(kc+k)*PAD + r0];
        const float2 bv = *(const float2*)&bb[k*64 + cg*2];
        a2[0][0] += av.x*bv.x; a2[0][1] += av.x*bv.y;
        a2[1][0] += av.y*bv.x; a2[1][1] += av.y*bv.y;
      }
    }
    #pragma unroll
    for (int i = 0; i < 2; ++i) {
      float2 v; v.x = a2[i][0]*inv_sd; v.y = a2[i][1]*inv_sd;
      *(float2*)&dfeat_ws[(size_t)(bn0 + r0 + i)*64 + cg*2] = v;
    }
  }
}

/* ---- backward pair kernel via E-factorization ---- */
__global__ __launch_bounds__(256) void k_bwd(
    const float* __restrict__ rvec,
    const int* __restrict__ tmap, const float* __restrict__ c_param,
    const float* __restrict__ S_ws, const float* __restrict__ dfeat_ws,
    float* __restrict__ dxp, float* __restrict__ dyp, float* __restrict__ dzp,
    float* __restrict__ virp, float* __restrict__ out)
{
  __shared__ float rv[768];
  __shared__ float c_lds[256];
  __shared__ float S_lds[64];
  __shared__ float df_lds[64];
  __shared__ float dS[64];
  __shared__ float E[64];
  __shared__ float wred[4*12];
  const int bn = blockIdx.x;
  const int b = bn >> 10;
  const int n = bn & (NN-1);
  const int tid = threadIdx.x;
  const int ti = tmap[n];
  c_lds[tid] = c_param[ti*256 + tid];
  const float* rb = rvec + (size_t)bn*MM*3;
  rv[tid] = rb[tid]; rv[tid+256] = rb[tid+256]; rv[tid+512] = rb[tid+512];
  if (tid < 64) {
    S_lds[tid] = S_ws[(size_t)bn*64 + tid];
    df_lds[tid] = dfeat_ws[(size_t)bn*64 + tid];
  }
  __syncthreads();
  if (tid < 64) {
    const int i = tid >> 2, a = tid & 3;
    float v = 0.f;
    #pragma unroll
    for (int q = 0; q < 4; ++q) v += df_lds[i*4+q]*S_lds[q*4+a];
    if (i < 4)
      for (int p = 0; p < 16; ++p) v += df_lds[p*4+i]*S_lds[p*4+a];
    dS[tid] = v;
  }
  __syncthreads();
  if (tid < 64) {
    const int tj = tid >> 5, rem = tid & 31;
    const int a = rem >> 3, k = rem & 7;
    float e = 0.f;
    #pragma unroll
    for (int p = 0; p < 16; ++p) e += dS[p*4+a]*c_lds[tj*128 + p*8 + k];
    E[tj*32 + a*8 + k] = e;
  }
  __syncthreads();
  const int m = tid;
  const float x = rv[3*m], y = rv[3*m+1], z = rv[3*m+2];
  const float r = sqrtf(x*x+y*y+z*z);
  const float inv_r = 1.0f/r;
  const float ux = x*inv_r, uy = y*inv_r, uz = z*inv_r;
  float u = 2.0f*(r - RMINf)/SPANf - 1.0f;
  u = fminf(fmaxf(u, -1.0f), 1.0f);
  const float arg = PIf*(r - RMINf)/SPANf;
  float sarg, carg;
  __sincosf(arg, &sarg, &carg);
  const float fc = 0.5f*(carg + 1.0f);
  const float dfc = -0.5f*(PIf/SPANf)*sarg;
  float T[BETA], dT[BETA];
  T[0]=1.f; T[1]=u; dT[0]=0.f; dT[1]=1.f;
  #pragma unroll
  for (int k=2;k<BETA;++k){
    T[k]  = 2.f*u*T[k-1] - T[k-2];
    dT[k] = 2.f*T[k-1] + 2.f*u*dT[k-1] - dT[k-2];
  }
  const float* Et = &E[(m >> 7)*32];
  float ta[4], tda[4];
  #pragma unroll
  for (int a = 0; a < 4; ++a) {
    float s = 0.f, sd2 = 0.f;
    #pragma unroll
    for (int k = 0; k < 8; ++k) {
      const float e = Et[a*8 + k];
      s   += T[k]*e;
      sd2 += dT[k]*e;
    }
    ta[a] = s; tda[a] = sd2;
  }
  const float dudr = 2.0f/SPANf;
  const float invM = 1.0f/(float)MM;
  float A = dfc*(ta[0] + ux*ta[1] + uy*ta[2] + uz*ta[3])
          + fc*dudr*(tda[0] + ux*tda[1] + uy*tda[2] + uz*tda[3]);
  float dq1 = fc*ta[1], dq2 = fc*ta[2], dq3 = fc*ta[3];
  A *= invM; dq1 *= invM; dq2 *= invM; dq3 *= invM;
  const float dqu = dq1*ux + dq2*uy + dq3*uz;
  const float d0 = A*ux + (dq1 - dqu*ux)*inv_r;
  const float d1 = A*uy + (dq2 - dqu*uy)*inv_r;
  const float d2 = A*uz + (dq3 - dqu*uz)*inv_r;
  const size_t gp = (size_t)bn*MM + m;
  dxp[gp] = d0; dyp[gp] = d1; dzp[gp] = d2;
  float red[12];
  red[0]=d0;    red[1]=d1;    red[2]=d2;
  red[3]=-x*d0; red[4]=-x*d1; red[5]=-x*d2;
  red[6]=-y*d0; red[7]=-y*d1; red[8]=-y*d2;
  red[9]=-z*d0; red[10]=-z*d1; red[11]=-z*d2;
  #pragma unroll
  for (int i=0;i<12;++i){
    float v = red[i];
    for (int o=32;o>0;o>>=1) v += __shfl_down(v,o);
    if ((tid & 63) == 0) wred[(tid>>6)*12 + i] = v;
  }
  __syncthreads();
  if (tid < 12) {
    const float v = wred[tid] + wred[12+tid] + wred[24+tid] + wred[36+tid];
    if (tid < 3) out[OUT_FORCE + (size_t)b*F3 + n*3 + tid] = v;
    else virp[(size_t)bn*9 + (tid-3)] = v;
  }
}

__global__ __launch_bounds__(256) void k_scatter(
    const int* __restrict__ nlist,
    const float* __restrict__ dxp, const float* __restrict__ dyp,
    const float* __restrict__ dzp, float* __restrict__ fpart_ws)
{
  __shared__ float fpart[F3];
  const int tid = threadIdx.x;
  const int blk = blockIdx.x;
  const int b = blk >> 5;
  const int g = blk & (NGROUP-1);
  for (int i = tid; i < F3; i += 256) fpart[i] = 0.f;
  __syncthreads();
  const size_t base = (size_t)b*PAIRS_PER_BATCH + (size_t)g*PAIRS_PER_GROUP;
  for (int i = 0; i < PAIRS_PER_GROUP/256; ++i) {
    const size_t gp = base + i*256 + tid;
    const int nl = nlist[gp];
    if (nl > 0) {
      const int j = nl - 1;
      atomicAdd(&fpart[j*3+0], -dxp[gp]);
      atomicAdd(&fpart[j*3+1], -dyp[gp]);
      atomicAdd(&fpart[j*3+2], -dzp[gp]);
    }
  }
  __syncthreads();
  float* dst = fpart_ws + (size_t)blk*F3;
  for (int i = tid; i < F3; i += 256) dst[i] = fpart[i];
}

__global__ __launch_bounds__(256) void k_reduce(
    const float* __restrict__ fpart_ws, const float* __restrict__ virp,
    float* __restrict__ out)
{
  const int tid = threadIdx.x;
  if (blockIdx.x == 102) {
    if (tid < 72) {
      const int b = tid / 9, v = tid % 9;
      float s = 0.f;
      for (int n = 0; n < NN; ++n) s += virp[((size_t)b*NN + n)*9 + v];
      out[OUT_VIR + tid] = s;
    }
    return;
  }
  const int e = blockIdx.x*256 + tid;
  if (e >= BB*F3) return;
  const int b = e / F3;
  const int i = e - b*F3;
  float s = 0.f;
  for (int g = 0; g < NGROUP; ++g)
    s += fpart_ws[((size_t)(b*NGROUP + g))*F3 + i];
  out[OUT_FORCE + e] += s;
}

extern "C" void kernel_launch(void* const* d_in, const int* in_sizes, int n_in,
                              void* d_out, int out_size, void* d_ws, size_t ws_size,
                              hipStream_t stream)
{
  const int*   nlist = (const int*)d_in[0];
  const int*   tmap  = (const int*)d_in[1];
  const float* rvec  = (const float*)d_in[2];
  const float* cpar  = (const float*)d_in[3];
  const float* W0 = (const float*)d_in[4];
  const float* b0 = (const float*)d_in[5];
  const float* W1 = (const float*)d_in[6];
  const float* b1 = (const float*)d_in[7];
  const float* W2 = (const float*)d_in[8];
  const float* b2 = (const float*)d_in[9];
  const float* Wout = (const float*)d_in[10];
  const float* bout = (const float*)d_in[11];
  float* out = (float*)d_out;
  float* ws = (float*)d_ws;
  float* S_ws   = ws + WS_S;
  float* df_ws  = ws + WS_DF;
  float* dxp    = ws + WS_DX;
  float* dyp    = ws + WS_DY;
  float* dzp    = ws + WS_DZ;
  float* statp  = ws + WS_STATP;
  float* mu_std = ws + WS_MUSTD;
  float* virp   = ws + WS_VIRP;
  float* fpartw = ws + WS_FPART;
  float* wt     = ws + WS_WT;

  hipMemsetAsync(d_out, 0, (size_t)out_size*sizeof(float), stream);

  k_transpose<<<320, 256, 0, stream>>>(W0, W1, W2, wt);
  k_feat <<<BB*NN, 256, 0, stream>>>(rvec, tmap, cpar, S_ws, statp);
  k_stats<<<1, 1024, 0, stream>>>(tmap, statp, mu_std);
  k_mlp  <<<(BB*NN)/MT, 256, 0, stream>>>(S_ws, tmap, mu_std, wt,
                                     W0,b0,W1,b1,W2,b2,Wout,bout, df_ws, out);
  k_bwd  <<<BB*NN, 256, 0, stream>>>(rvec, tmap, cpar, S_ws, df_ws,
                                     dxp, dyp, dzp, virp, out);
  k_scatter<<<BB*NGROUP, 256, 0, stream>>>(nlist, dxp, dyp, dzp, fpartw);
  k_reduce <<<103, 256, 0, stream>>>(fpartw, virp, out);
}

// Round 5
// 264.351 us; speedup vs baseline: 3.1755x; 3.1755x over previous
//
#include <hip/hip_runtime.h>
#include <math.h>

#define BB 8
#define NN 1024
#define MM 256
#define BETA 8
#define M1 16
#define NFEAT 64
#define HH 128
#define NTOT 1088   /* N + NGHOST */
#define F3 (NTOT*3) /* 3264 */
#define RMINf 0.5f
#define SPANf 5.5f
#define PIf 3.14159265358979323846f

#define OUT_EI 8
#define OUT_FORCE 8200          /* 8 + 8192 */
#define OUT_VIR 34312           /* 8200 + 8*1088*3 */

#define NGROUP 32               /* scatter groups per batch */
#define PAIRS_PER_BATCH (NN*MM) /* 262144 */
#define PAIRS_PER_GROUP (PAIRS_PER_BATCH/NGROUP) /* 8192 */

#define MT 16                   /* atoms per MLP tile */
#define PAD 18                  /* activation LDS leading-dim pad (b64-aligned) */

/* workspace float offsets */
#define WS_S     0
#define WS_DF    (WS_S + 8192*64)
#define WS_DX    (WS_DF + 8192*64)
#define WS_DY    (WS_DX + 8192*256)
#define WS_DZ    (WS_DY + 8192*256)
#define WS_STATP (WS_DZ + 8192*256)      /* 8192*2 */
#define WS_MUSTD (WS_STATP + 8192*2)     /* 4 */
#define WS_VIRP  (WS_MUSTD + 4)          /* 8192*9 */
#define WS_FPART (WS_VIRP + 8192*9)      /* 8*32*3264 */
#define WS_WT    (WS_FPART + BB*NGROUP*F3) /* 81920 */
#define WT0_OFF  0
#define WT1_OFF  16384
#define WT2_OFF  49152

__global__ __launch_bounds__(256) void k_transpose(
    const float* __restrict__ W0, const float* __restrict__ W1,
    const float* __restrict__ W2, float* __restrict__ wt)
{
  const int idx = blockIdx.x*256 + threadIdx.x;
  if (idx < 16384) {
    const int t = idx >> 13, rem = idx & 8191;
    const int j = rem >> 6, f = rem & 63;
    wt[WT0_OFF + idx] = W0[t*8192 + f*128 + j];
  } else if (idx < 49152) {
    const int i = idx - 16384;
    const int t = i >> 14, rem = i & 16383;
    const int j = rem >> 7, f = rem & 127;
    wt[WT1_OFF + i] = W1[t*16384 + f*128 + j];
  } else if (idx < 81920) {
    const int i = idx - 49152;
    const int t = i >> 14, rem = i & 16383;
    const int j = rem >> 7, f = rem & 127;
    wt[WT2_OFF + i] = W2[t*16384 + f*128 + j];
  }
}

/* ---- features via U-factorization: S[p][a] = (1/M) sum_tj sum_k c[tj][p][k] U[tj][k][a] ---- */
__global__ __launch_bounds__(256) void k_feat(
    const float* __restrict__ rvec, const int* __restrict__ tmap,
    const float* __restrict__ c_param, float* __restrict__ S_ws,
    float* __restrict__ statp)
{
  __shared__ float rv[768];
  __shared__ float c_lds[256];
  __shared__ float prod[256*33];
  __shared__ float part[8*32];
  __shared__ float U[2*32];
  __shared__ float S_lds[64];
  const int bn = blockIdx.x;
  const int n = bn & (NN-1);
  const int tid = threadIdx.x;
  const int ti = tmap[n];
  c_lds[tid] = c_param[ti*256 + tid];
  const float* rb = rvec + (size_t)bn*MM*3;
  rv[tid] = rb[tid]; rv[tid+256] = rb[tid+256]; rv[tid+512] = rb[tid+512];
  __syncthreads();
  const int m = tid;
  const float x = rv[3*m], y = rv[3*m+1], z = rv[3*m+2];
  const float r = sqrtf(x*x + y*y + z*z);
  const float inv_r = 1.0f / r;
  const float ux = x*inv_r, uy = y*inv_r, uz = z*inv_r;
  float u = 2.0f*(r - RMINf)/SPANf - 1.0f;
  u = fminf(fmaxf(u, -1.0f), 1.0f);
  const float fc = 0.5f*(__cosf(PIf*(r - RMINf)/SPANf) + 1.0f);
  float T[BETA];
  T[0] = 1.0f; T[1] = u;
  #pragma unroll
  for (int k = 2; k < BETA; ++k) T[k] = 2.0f*u*T[k-1] - T[k-2];
  float* pr = &prod[m*33];
  #pragma unroll
  for (int k = 0; k < BETA; ++k) {
    const float ft = fc*T[k];
    pr[k*4+0] = ft;
    pr[k*4+1] = ft*ux;
    pr[k*4+2] = ft*uy;
    pr[k*4+3] = ft*uz;
  }
  __syncthreads();
  {
    const int c = tid & 31, oct = tid >> 5;
    const int m0 = oct*32;
    float s = 0.f;
    #pragma unroll 8
    for (int i = 0; i < 32; ++i) s += prod[(m0+i)*33 + c];
    part[oct*32 + c] = s;
  }
  __syncthreads();
  if (tid < 64) {
    const int tj = tid >> 5, c = tid & 31;
    U[tid] = part[(tj*4+0)*32+c] + part[(tj*4+1)*32+c]
           + part[(tj*4+2)*32+c] + part[(tj*4+3)*32+c];
  }
  __syncthreads();
  if (tid < 64) {
    const int p = tid >> 2, a = tid & 3;
    float s = 0.f;
    #pragma unroll
    for (int tj = 0; tj < 2; ++tj)
      #pragma unroll
      for (int k = 0; k < 8; ++k)
        s += c_lds[tj*128 + p*8 + k] * U[tj*32 + k*4 + a];
    s *= (1.0f/(float)MM);
    S_lds[tid] = s;
    S_ws[(size_t)bn*64 + tid] = s;
  }
  __syncthreads();
  if (tid < 64) {
    const int p = tid >> 2, q = tid & 3;
    float f = 0.f;
    #pragma unroll
    for (int a = 0; a < 4; ++a) f += S_lds[p*4+a]*S_lds[q*4+a];
    float fs = f, fss = f*f;
    for (int o = 32; o > 0; o >>= 1) { fs += __shfl_down(fs, o); fss += __shfl_down(fss, o); }
    if (tid == 0) { statp[bn*2+0] = fs; statp[bn*2+1] = fss; }
  }
}

__global__ __launch_bounds__(1024) void k_stats(
    const int* __restrict__ tmap, const float* __restrict__ statp,
    float* __restrict__ mu_std)
{
  __shared__ float wred[16*5];
  const int tid = threadIdx.x;
  const int ti = tmap[tid];
  float fs = 0.f, fss = 0.f;
  for (int b = 0; b < BB; ++b) {
    fs  += statp[(b*NN + tid)*2 + 0];
    fss += statp[(b*NN + tid)*2 + 1];
  }
  float v[5];
  v[0] = (ti == 0) ? fs  : 0.f;
  v[1] = (ti == 0) ? fss : 0.f;
  v[2] = (ti == 1) ? fs  : 0.f;
  v[3] = (ti == 1) ? fss : 0.f;
  v[4] = (ti == 0) ? 1.f : 0.f;
  for (int o = 32; o > 0; o >>= 1)
    for (int i = 0; i < 5; ++i) v[i] += __shfl_down(v[i], o);
  if ((tid & 63) == 0)
    for (int i = 0; i < 5; ++i) wred[(tid >> 6)*5 + i] = v[i];
  __syncthreads();
  if (tid == 0) {
    float s[5] = {0,0,0,0,0};
    for (int w = 0; w < 16; ++w)
      for (int i = 0; i < 5; ++i) s[i] += wred[w*5 + i];
    const float c0 = s[4];
    for (int t = 0; t < 2; ++t) {
      const float cn = (t == 0) ? c0 : ((float)NN - c0);
      const float cnt = cn * (float)BB * (float)NFEAT;
      const float mu = s[t*2+0] / cnt;
      const float var = (s[t*2+1] - cnt*mu*mu) / (cnt - 1.0f);
      mu_std[t*2+0] = mu;
      mu_std[t*2+1] = sqrtf(fmaxf(var, 1e-20f));
    }
  }
}

/* ---- tiled MLP: 16 atoms/block, 2x4 register tile, activations in LDS ----
   unroll 4 on the k-loop + launch_bounds(256,3): cap the scheduler's
   ds_read hoisting window so VGPR stays < 168 (round-4 full unroll hit the
   256 cap and spilled ~1.4 GB of scratch traffic). */
#define GEMM128(WPTR, K, ABUF) \
  for (int kc = 0; kc < (K); kc += 32) { \
    __syncthreads(); \
    { const float4* _s = (const float4*)((WPTR) + kc*128); \
      float4* _d = (float4*)bb; \
      _d[tid] = _s[tid]; _d[tid+256] = _s[tid+256]; \
      _d[tid+512] = _s[tid+512]; _d[tid+768] = _s[tid+768]; } \
    __syncthreads(); \
    _Pragma("unroll 4") \
    for (int k = 0; k < 32; ++k) { \
      const float2 av = *(const float2*)&(ABUF)[(kc+k)*PAD + r0]; \
      const float4 bv = *(const float4*)&bb[k*128 + c0]; \
      acc[0][0] += av.x*bv.x; acc[0][1] += av.x*bv.y; acc[0][2] += av.x*bv.z; acc[0][3] += av.x*bv.w; \
      acc[1][0] += av.y*bv.x; acc[1][1] += av.y*bv.y; acc[1][2] += av.y*bv.z; acc[1][3] += av.y*bv.w; \
    } \
  }

__global__ __launch_bounds__(256, 3) void k_mlp(
    const float* __restrict__ S_ws, const int* __restrict__ tmap,
    const float* __restrict__ mu_std, const float* __restrict__ wt,
    const float* __restrict__ W0, const float* __restrict__ b0,
    const float* __restrict__ W1, const float* __restrict__ b1,
    const float* __restrict__ W2, const float* __restrict__ b2,
    const float* __restrict__ Wout, const float* __restrict__ bout,
    float* __restrict__ dfeat_ws, float* __restrict__ out)
{
  __shared__ float xb[64*PAD];     /* normalized feat, k-major */
  __shared__ float t0b[128*PAD];   /* tanh(z0) */
  __shared__ float h1b[128*PAD];   /* t1 + t0 */
  __shared__ float dzb[128*PAD];   /* current backward dz (A operand) */
  __shared__ float bb[32*128];     /* weight chunk */
  __shared__ float sl[MT*64];
  __shared__ float es[MT];
  const int tb = blockIdx.x;
  const int bn0 = tb*MT;
  const int b = bn0 >> 10;
  const int tid = threadIdx.x;
  const int t = tmap[bn0 & (NN-1)];
  const int rg = tid >> 5, cg = tid & 31;
  const int r0 = rg*2;            /* 2 atoms per thread */
  const int c0 = cg*4;            /* 4 cols per thread */
  {
    const float4* src = (const float4*)(S_ws + (size_t)bn0*64);
    ((float4*)sl)[tid] = src[tid];
  }
  __syncthreads();
  const float mu = mu_std[t*2], sd = mu_std[t*2+1];
  const float inv_sd = 1.0f/sd;
  #pragma unroll
  for (int i = 0; i < 4; ++i) {
    const int e = i*256 + tid;
    const int r = e >> 6, f = e & 63;
    const int p = f >> 2, q = f & 3;
    const float* Sr = &sl[r*64];
    float s = 0.f;
    #pragma unroll
    for (int a = 0; a < 4; ++a) s += Sr[p*4+a]*Sr[q*4+a];
    xb[f*PAD + r] = (s - mu)*inv_sd;
  }

  float acc[2][4], dh1r[2][4], wor[4];

  /* L0: z0 = x @ W0 + b0, K=64 */
  {
    const float* bp = b0 + t*HH;
    const float bj0 = bp[c0], bj1 = bp[c0+1], bj2 = bp[c0+2], bj3 = bp[c0+3];
    #pragma unroll
    for (int i = 0; i < 2; ++i) { acc[i][0]=bj0; acc[i][1]=bj1; acc[i][2]=bj2; acc[i][3]=bj3; }
  }
  GEMM128(W0 + (size_t)t*NFEAT*HH, 64, xb);
  __syncthreads();
  #pragma unroll
  for (int i = 0; i < 2; ++i)
    #pragma unroll
    for (int j = 0; j < 4; ++j) t0b[(c0+j)*PAD + r0+i] = tanhf(acc[i][j]);

  /* L1: h1 = tanh(t0 @ W1 + b1) + t0 */
  {
    const float* bp = b1 + t*HH;
    const float bj0 = bp[c0], bj1 = bp[c0+1], bj2 = bp[c0+2], bj3 = bp[c0+3];
    #pragma unroll
    for (int i = 0; i < 2; ++i) { acc[i][0]=bj0; acc[i][1]=bj1; acc[i][2]=bj2; acc[i][3]=bj3; }
  }
  GEMM128(W1 + (size_t)t*HH*HH, 128, t0b);
  __syncthreads();
  #pragma unroll
  for (int i = 0; i < 2; ++i)
    #pragma unroll
    for (int j = 0; j < 4; ++j)
      h1b[(c0+j)*PAD + r0+i] = tanhf(acc[i][j]) + t0b[(c0+j)*PAD + r0+i];

  /* L2: z2 = h1 @ W2 + b2 */
  {
    const float* bp = b2 + t*HH;
    const float bj0 = bp[c0], bj1 = bp[c0+1], bj2 = bp[c0+2], bj3 = bp[c0+3];
    #pragma unroll
    for (int i = 0; i < 2; ++i) { acc[i][0]=bj0; acc[i][1]=bj1; acc[i][2]=bj2; acc[i][3]=bj3; }
  }
  GEMM128(W2 + (size_t)t*HH*HH, 128, h1b);
  __syncthreads();

  #pragma unroll
  for (int j = 0; j < 4; ++j) wor[j] = Wout[t*HH + c0 + j];

  /* energy + dz2 */
  {
    float pr0 = 0.f, pr1 = 0.f;
    #pragma unroll
    for (int i = 0; i < 2; ++i)
      #pragma unroll
      for (int j = 0; j < 4; ++j) {
        const float t2 = tanhf(acc[i][j]);
        const float h2 = t2 + h1b[(c0+j)*PAD + r0+i];
        if (i == 0) pr0 += h2*wor[j]; else pr1 += h2*wor[j];
        dzb[(c0+j)*PAD + r0+i] = wor[j]*(1.0f - t2*t2);
      }
    for (int o = 16; o > 0; o >>= 1) {
      pr0 += __shfl_down(pr0, o, 32);
      pr1 += __shfl_down(pr1, o, 32);
    }
    if (cg == 0) { es[r0] = pr0; es[r0+1] = pr1; }
  }
  __syncthreads();
  if (tid < MT) out[OUT_EI + bn0 + tid] = es[tid] + bout[t];
  if (tid == 0) {
    float s = 0.f;
    for (int i = 0; i < MT; ++i) s += es[i];
    atomicAdd(&out[b], s + (float)MT*bout[t]);
  }

  /* dh1 = wo + dz2 @ W2^T */
  #pragma unroll
  for (int i = 0; i < 2; ++i)
    #pragma unroll
    for (int j = 0; j < 4; ++j) acc[i][j] = wor[j];
  GEMM128(wt + WT2_OFF + (size_t)t*HH*HH, 128, dzb);
  #pragma unroll
  for (int i = 0; i < 2; ++i)
    #pragma unroll
    for (int j = 0; j < 4; ++j) dh1r[i][j] = acc[i][j];
  __syncthreads();
  /* dz1 = dh1 * (1 - t1^2), t1 = h1 - t0 */
  #pragma unroll
  for (int i = 0; i < 2; ++i)
    #pragma unroll
    for (int j = 0; j < 4; ++j) {
      const float t1 = h1b[(c0+j)*PAD + r0+i] - t0b[(c0+j)*PAD + r0+i];
      dzb[(c0+j)*PAD + r0+i] = dh1r[i][j]*(1.0f - t1*t1);
    }
  /* dh0 = dh1 + dz1 @ W1^T */
  #pragma unroll
  for (int i = 0; i < 2; ++i)
    #pragma unroll
    for (int j = 0; j < 4; ++j) acc[i][j] = dh1r[i][j];
  GEMM128(wt + WT1_OFF + (size_t)t*HH*HH, 128, dzb);
  __syncthreads();
  /* dz0 = dh0 * (1 - t0^2) */
  #pragma unroll
  for (int i = 0; i < 2; ++i)
    #pragma unroll
    for (int j = 0; j < 4; ++j) {
      const float t0 = t0b[(c0+j)*PAD + r0+i];
      dzb[(c0+j)*PAD + r0+i] = acc[i][j]*(1.0f - t0*t0);
    }
  /* dx = dz0 @ W0^T : MTx64 out; 2 atoms x 2 feats per thread */
  {
    float a2[2][2];
    a2[0][0]=0.f; a2[0][1]=0.f; a2[1][0]=0.f; a2[1][1]=0.f;
    const float* WT0t = wt + WT0_OFF + (size_t)t*HH*NFEAT;
    for (int kc = 0; kc < 128; kc += 32) {
      __syncthreads();
      { const float4* _s = (const float4*)(WT0t + kc*64);
        float4* _d = (float4*)bb;
        _d[tid] = _s[tid]; _d[tid+256] = _s[tid+256]; }
      __syncthreads();
      #pragma unroll 4
      for (int k = 0; k < 32; ++k) {
        const float2 av = *(const float2*)&dzb[(kc+k)*PAD + r0];
        const float2 bv = *(const float2*)&bb[k*64 + cg*2];
        a2[0][0] += av.x*bv.x; a2[0][1] += av.x*bv.y;
        a2[1][0] += av.y*bv.x; a2[1][1] += av.y*bv.y;
      }
    }
    #pragma unroll
    for (int i = 0; i < 2; ++i) {
      float2 v; v.x = a2[i][0]*inv_sd; v.y = a2[i][1]*inv_sd;
      *(float2*)&dfeat_ws[(size_t)(bn0 + r0 + i)*64 + cg*2] = v;
    }
  }
}

/* ---- backward pair kernel via E-factorization ---- */
__global__ __launch_bounds__(256) void k_bwd(
    const float* __restrict__ rvec,
    const int* __restrict__ tmap, const float* __restrict__ c_param,
    const float* __restrict__ S_ws, const float* __restrict__ dfeat_ws,
    float* __restrict__ dxp, float* __restrict__ dyp, float* __restrict__ dzp,
    float* __restrict__ virp, float* __restrict__ out)
{
  __shared__ float rv[768];
  __shared__ float c_lds[256];
  __shared__ float S_lds[64];
  __shared__ float df_lds[64];
  __shared__ float dS[64];
  __shared__ float E[64];
  __shared__ float wred[4*12];
  const int bn = blockIdx.x;
  const int b = bn >> 10;
  const int n = bn & (NN-1);
  const int tid = threadIdx.x;
  const int ti = tmap[n];
  c_lds[tid] = c_param[ti*256 + tid];
  const float* rb = rvec + (size_t)bn*MM*3;
  rv[tid] = rb[tid]; rv[tid+256] = rb[tid+256]; rv[tid+512] = rb[tid+512];
  if (tid < 64) {
    S_lds[tid] = S_ws[(size_t)bn*64 + tid];
    df_lds[tid] = dfeat_ws[(size_t)bn*64 + tid];
  }
  __syncthreads();
  if (tid < 64) {
    const int i = tid >> 2, a = tid & 3;
    float v = 0.f;
    #pragma unroll
    for (int q = 0; q < 4; ++q) v += df_lds[i*4+q]*S_lds[q*4+a];
    if (i < 4)
      for (int p = 0; p < 16; ++p) v += df_lds[p*4+i]*S_lds[p*4+a];
    dS[tid] = v;
  }
  __syncthreads();
  if (tid < 64) {
    const int tj = tid >> 5, rem = tid & 31;
    const int a = rem >> 3, k = rem & 7;
    float e = 0.f;
    #pragma unroll
    for (int p = 0; p < 16; ++p) e += dS[p*4+a]*c_lds[tj*128 + p*8 + k];
    E[tj*32 + a*8 + k] = e;
  }
  __syncthreads();
  const int m = tid;
  const float x = rv[3*m], y = rv[3*m+1], z = rv[3*m+2];
  const float r = sqrtf(x*x+y*y+z*z);
  const float inv_r = 1.0f/r;
  const float ux = x*inv_r, uy = y*inv_r, uz = z*inv_r;
  float u = 2.0f*(r - RMINf)/SPANf - 1.0f;
  u = fminf(fmaxf(u, -1.0f), 1.0f);
  const float arg = PIf*(r - RMINf)/SPANf;
  float sarg, carg;
  __sincosf(arg, &sarg, &carg);
  const float fc = 0.5f*(carg + 1.0f);
  const float dfc = -0.5f*(PIf/SPANf)*sarg;
  float T[BETA], dT[BETA];
  T[0]=1.f; T[1]=u; dT[0]=0.f; dT[1]=1.f;
  #pragma unroll
  for (int k=2;k<BETA;++k){
    T[k]  = 2.f*u*T[k-1] - T[k-2];
    dT[k] = 2.f*T[k-1] + 2.f*u*dT[k-1] - dT[k-2];
  }
  const float* Et = &E[(m >> 7)*32];
  float ta[4], tda[4];
  #pragma unroll
  for (int a = 0; a < 4; ++a) {
    float s = 0.f, sd2 = 0.f;
    #pragma unroll
    for (int k = 0; k < 8; ++k) {
      const float e = Et[a*8 + k];
      s   += T[k]*e;
      sd2 += dT[k]*e;
    }
    ta[a] = s; tda[a] = sd2;
  }
  const float dudr = 2.0f/SPANf;
  const float invM = 1.0f/(float)MM;
  float A = dfc*(ta[0] + ux*ta[1] + uy*ta[2] + uz*ta[3])
          + fc*dudr*(tda[0] + ux*tda[1] + uy*tda[2] + uz*tda[3]);
  float dq1 = fc*ta[1], dq2 = fc*ta[2], dq3 = fc*ta[3];
  A *= invM; dq1 *= invM; dq2 *= invM; dq3 *= invM;
  const float dqu = dq1*ux + dq2*uy + dq3*uz;
  const float d0 = A*ux + (dq1 - dqu*ux)*inv_r;
  const float d1 = A*uy + (dq2 - dqu*uy)*inv_r;
  const float d2 = A*uz + (dq3 - dqu*uz)*inv_r;
  const size_t gp = (size_t)bn*MM + m;
  dxp[gp] = d0; dyp[gp] = d1; dzp[gp] = d2;
  float red[12];
  red[0]=d0;    red[1]=d1;    red[2]=d2;
  red[3]=-x*d0; red[4]=-x*d1; red[5]=-x*d2;
  red[6]=-y*d0; red[7]=-y*d1; red[8]=-y*d2;
  red[9]=-z*d0; red[10]=-z*d1; red[11]=-z*d2;
  #pragma unroll
  for (int i=0;i<12;++i){
    float v = red[i];
    for (int o=32;o>0;o>>=1) v += __shfl_down(v,o);
    if ((tid & 63) == 0) wred[(tid>>6)*12 + i] = v;
  }
  __syncthreads();
  if (tid < 12) {
    const float v = wred[tid] + wred[12+tid] + wred[24+tid] + wred[36+tid];
    if (tid < 3) out[OUT_FORCE + (size_t)b*F3 + n*3 + tid] = v;
    else virp[(size_t)bn*9 + (tid-3)] = v;
  }
}

__global__ __launch_bounds__(256) void k_scatter(
    const int* __restrict__ nlist,
    const float* __restrict__ dxp, const float* __restrict__ dyp,
    const float* __restrict__ dzp, float* __restrict__ fpart_ws)
{
  __shared__ float fpart[F3];
  const int tid = threadIdx.x;
  const int blk = blockIdx.x;
  const int b = blk >> 5;
  const int g = blk & (NGROUP-1);
  for (int i = tid; i < F3; i += 256) fpart[i] = 0.f;
  __syncthreads();
  const size_t base = (size_t)b*PAIRS_PER_BATCH + (size_t)g*PAIRS_PER_GROUP;
  for (int i = 0; i < PAIRS_PER_GROUP/256; ++i) {
    const size_t gp = base + i*256 + tid;
    const int nl = nlist[gp];
    if (nl > 0) {
      const int j = nl - 1;
      atomicAdd(&fpart[j*3+0], -dxp[gp]);
      atomicAdd(&fpart[j*3+1], -dyp[gp]);
      atomicAdd(&fpart[j*3+2], -dzp[gp]);
    }
  }
  __syncthreads();
  float* dst = fpart_ws + (size_t)blk*F3;
  for (int i = tid; i < F3; i += 256) dst[i] = fpart[i];
}

__global__ __launch_bounds__(256) void k_reduce(
    const float* __restrict__ fpart_ws, const float* __restrict__ virp,
    float* __restrict__ out)
{
  const int tid = threadIdx.x;
  if (blockIdx.x == 102) {
    if (tid < 72) {
      const int b = tid / 9, v = tid % 9;
      float s = 0.f;
      for (int n = 0; n < NN; ++n) s += virp[((size_t)b*NN + n)*9 + v];
      out[OUT_VIR + tid] = s;
    }
    return;
  }
  const int e = blockIdx.x*256 + tid;
  if (e >= BB*F3) return;
  const int b = e / F3;
  const int i = e - b*F3;
  float s = 0.f;
  for (int g = 0; g < NGROUP; ++g)
    s += fpart_ws[((size_t)(b*NGROUP + g))*F3 + i];
  out[OUT_FORCE + e] += s;
}

extern "C" void kernel_launch(void* const* d_in, const int* in_sizes, int n_in,
                              void* d_out, int out_size, void* d_ws, size_t ws_size,
                              hipStream_t stream)
{
  const int*   nlist = (const int*)d_in[0];
  const int*   tmap  = (const int*)d_in[1];
  const float* rvec  = (const float*)d_in[2];
  const float* cpar  = (const float*)d_in[3];
  const float* W0 = (const float*)d_in[4];
  const float* b0 = (const float*)d_in[5];
  const float* W1 = (const float*)d_in[6];
  const float* b1 = (const float*)d_in[7];
  const float* W2 = (const float*)d_in[8];
  const float* b2 = (const float*)d_in[9];
  const float* Wout = (const float*)d_in[10];
  const float* bout = (const float*)d_in[11];
  float* out = (float*)d_out;
  float* ws = (float*)d_ws;
  float* S_ws   = ws + WS_S;
  float* df_ws  = ws + WS_DF;
  float* dxp    = ws + WS_DX;
  float* dyp    = ws + WS_DY;
  float* dzp    = ws + WS_DZ;
  float* statp  = ws + WS_STATP;
  float* mu_std = ws + WS_MUSTD;
  float* virp   = ws + WS_VIRP;
  float* fpartw = ws + WS_FPART;
  float* wt     = ws + WS_WT;

  hipMemsetAsync(d_out, 0, (size_t)out_size*sizeof(float), stream);

  k_transpose<<<320, 256, 0, stream>>>(W0, W1, W2, wt);
  k_feat <<<BB*NN, 256, 0, stream>>>(rvec, tmap, cpar, S_ws, statp);
  k_stats<<<1, 1024, 0, stream>>>(tmap, statp, mu_std);
  k_mlp  <<<(BB*NN)/MT, 256, 0, stream>>>(S_ws, tmap, mu_std, wt,
                                     W0,b0,W1,b1,W2,b2,Wout,bout, df_ws, out);
  k_bwd  <<<BB*NN, 256, 0, stream>>>(rvec, tmap, cpar, S_ws, df_ws,
                                     dxp, dyp, dzp, virp, out);
  k_scatter<<<BB*NGROUP, 256, 0, stream>>>(nlist, dxp, dyp, dzp, fpartw);
  k_reduce <<<103, 256, 0, stream>>>(fpartw, virp, out);
}

// Round 6
// 221.725 us; speedup vs baseline: 3.7860x; 1.1922x over previous
//
#include <hip/hip_runtime.h>
#include <math.h>

#define BB 8
#define NN 1024
#define MM 256
#define BETA 8
#define M1 16
#define NFEAT 64
#define HH 128
#define NTOT 1088   /* N + NGHOST */
#define F3 (NTOT*3) /* 3264 */
#define RMINf 0.5f
#define SPANf 5.5f
#define PIf 3.14159265358979323846f

#define OUT_EI 8
#define OUT_FORCE 8200          /* 8 + 8192 */
#define OUT_VIR 34312           /* 8200 + 8*1088*3 */

#define NGROUP 32               /* scatter groups per batch */
#define PAIRS_PER_BATCH (NN*MM) /* 262144 */
#define PAIRS_PER_GROUP (PAIRS_PER_BATCH/NGROUP) /* 8192 */

#define MT 16                   /* atoms per MLP tile */
#define PAD 18                  /* activation LDS leading-dim pad (b64-aligned) */

/* workspace float offsets */
#define WS_S     0
#define WS_DF    (WS_S + 8192*64)
#define WS_DX    (WS_DF + 8192*64)
#define WS_DY    (WS_DX + 8192*256)
#define WS_DZ    (WS_DY + 8192*256)
#define WS_STATP (WS_DZ + 8192*256)      /* 8192*2 */
#define WS_MUSTD (WS_STATP + 8192*2)     /* 4 (unused now) */
#define WS_VIRP  (WS_MUSTD + 4)          /* 8192*9 */
#define WS_FPART (WS_VIRP + 8192*9)      /* 8*32*3264 */
#define WS_WT    (WS_FPART + BB*NGROUP*F3) /* 81920 */
#define WS_CF    WS_WT                   /* cf aliases wt: wt dead after k_mlp,
                                            cf produced by k_bwd (later) */
#define WT0_OFF  0
#define WT1_OFF  16384
#define WT2_OFF  49152

__device__ __forceinline__ float ftanh(float x) {
  /* 1 - 2/(e^{2x}+1): exact +-1 saturation (e->inf => 1, e->0 => -1) */
  const float e = __expf(2.0f*x);
  return 1.0f - 2.0f/(e + 1.0f);
}

/* ---- features via U-factorization + fused weight transpose blocks ---- */
__global__ __launch_bounds__(256) void k_feat(
    const float* __restrict__ rvec, const int* __restrict__ tmap,
    const float* __restrict__ c_param, float* __restrict__ S_ws,
    float* __restrict__ statp,
    const float* __restrict__ W0, const float* __restrict__ W1,
    const float* __restrict__ W2, float* __restrict__ wt)
{
  __shared__ float rv[768];
  __shared__ float c_lds[256];
  __shared__ float prod[256*33];
  __shared__ float part[8*32];
  __shared__ float U[2*32];
  __shared__ float S_lds[64];
  const int tid = threadIdx.x;
  if (blockIdx.x >= BB*NN) {
    /* weight-transpose tail blocks */
    const int idx = (blockIdx.x - BB*NN)*256 + tid;
    if (idx < 16384) {
      const int t = idx >> 13, rem = idx & 8191;
      const int j = rem >> 6, f = rem & 63;
      wt[WT0_OFF + idx] = W0[t*8192 + f*128 + j];
    } else if (idx < 49152) {
      const int i = idx - 16384;
      const int t = i >> 14, rem = i & 16383;
      const int j = rem >> 7, f = rem & 127;
      wt[WT1_OFF + i] = W1[t*16384 + f*128 + j];
    } else if (idx < 81920) {
      const int i = idx - 49152;
      const int t = i >> 14, rem = i & 16383;
      const int j = rem >> 7, f = rem & 127;
      wt[WT2_OFF + i] = W2[t*16384 + f*128 + j];
    }
    return;
  }
  const int bn = blockIdx.x;
  const int n = bn & (NN-1);
  const int ti = tmap[n];
  c_lds[tid] = c_param[ti*256 + tid];
  const float* rb = rvec + (size_t)bn*MM*3;
  rv[tid] = rb[tid]; rv[tid+256] = rb[tid+256]; rv[tid+512] = rb[tid+512];
  __syncthreads();
  const int m = tid;
  const float x = rv[3*m], y = rv[3*m+1], z = rv[3*m+2];
  const float r = sqrtf(x*x + y*y + z*z);
  const float inv_r = 1.0f / r;
  const float ux = x*inv_r, uy = y*inv_r, uz = z*inv_r;
  float u = 2.0f*(r - RMINf)/SPANf - 1.0f;
  u = fminf(fmaxf(u, -1.0f), 1.0f);
  const float fc = 0.5f*(__cosf(PIf*(r - RMINf)/SPANf) + 1.0f);
  float T[BETA];
  T[0] = 1.0f; T[1] = u;
  #pragma unroll
  for (int k = 2; k < BETA; ++k) T[k] = 2.0f*u*T[k-1] - T[k-2];
  float* pr = &prod[m*33];
  #pragma unroll
  for (int k = 0; k < BETA; ++k) {
    const float ft = fc*T[k];
    pr[k*4+0] = ft;
    pr[k*4+1] = ft*ux;
    pr[k*4+2] = ft*uy;
    pr[k*4+3] = ft*uz;
  }
  __syncthreads();
  {
    const int c = tid & 31, oct = tid >> 5;
    const int m0 = oct*32;
    float s = 0.f;
    #pragma unroll 8
    for (int i = 0; i < 32; ++i) s += prod[(m0+i)*33 + c];
    part[oct*32 + c] = s;
  }
  __syncthreads();
  if (tid < 64) {
    const int tj = tid >> 5, c = tid & 31;
    U[tid] = part[(tj*4+0)*32+c] + part[(tj*4+1)*32+c]
           + part[(tj*4+2)*32+c] + part[(tj*4+3)*32+c];
  }
  __syncthreads();
  if (tid < 64) {
    const int p = tid >> 2, a = tid & 3;
    float s = 0.f;
    #pragma unroll
    for (int tj = 0; tj < 2; ++tj)
      #pragma unroll
      for (int k = 0; k < 8; ++k)
        s += c_lds[tj*128 + p*8 + k] * U[tj*32 + k*4 + a];
    s *= (1.0f/(float)MM);
    S_lds[tid] = s;
    S_ws[(size_t)bn*64 + tid] = s;
  }
  __syncthreads();
  if (tid < 64) {
    const int p = tid >> 2, q = tid & 3;
    float f = 0.f;
    #pragma unroll
    for (int a = 0; a < 4; ++a) f += S_lds[p*4+a]*S_lds[q*4+a];
    float fs = f, fss = f*f;
    for (int o = 32; o > 0; o >>= 1) { fs += __shfl_down(fs, o); fss += __shfl_down(fss, o); }
    if (tid == 0) { statp[bn*2+0] = fs; statp[bn*2+1] = fss; }
  }
}

/* ---- tiled MLP (round-5 GEMM core, proven no-spill) + in-block stats ---- */
#define GEMM128(WPTR, K, ABUF) \
  for (int kc = 0; kc < (K); kc += 32) { \
    __syncthreads(); \
    { const float4* _s = (const float4*)((WPTR) + kc*128); \
      float4* _d = (float4*)bb; \
      _d[tid] = _s[tid]; _d[tid+256] = _s[tid+256]; \
      _d[tid+512] = _s[tid+512]; _d[tid+768] = _s[tid+768]; } \
    __syncthreads(); \
    _Pragma("unroll 4") \
    for (int k = 0; k < 32; ++k) { \
      const float2 av = *(const float2*)&(ABUF)[(kc+k)*PAD + r0]; \
      const float4 bv = *(const float4*)&bb[k*128 + c0]; \
      acc[0][0] += av.x*bv.x; acc[0][1] += av.x*bv.y; acc[0][2] += av.x*bv.z; acc[0][3] += av.x*bv.w; \
      acc[1][0] += av.y*bv.x; acc[1][1] += av.y*bv.y; acc[1][2] += av.y*bv.z; acc[1][3] += av.y*bv.w; \
    } \
  }

__global__ __launch_bounds__(256, 3) void k_mlp(
    const float* __restrict__ S_ws, const int* __restrict__ tmap,
    const float* __restrict__ statp, const float* __restrict__ wt,
    const float* __restrict__ W0, const float* __restrict__ b0,
    const float* __restrict__ W1, const float* __restrict__ b1,
    const float* __restrict__ W2, const float* __restrict__ b2,
    const float* __restrict__ Wout, const float* __restrict__ bout,
    float* __restrict__ dfeat_ws, float* __restrict__ out)
{
  __shared__ float xb[64*PAD];
  __shared__ float t0b[128*PAD];
  __shared__ float h1b[128*PAD];
  __shared__ float dzb[128*PAD];
  __shared__ float bb[32*128];
  __shared__ float sl[MT*64];
  __shared__ float es[MT];
  __shared__ float srd[8];
  __shared__ float muSd[2];
  const int tb = blockIdx.x;
  const int bn0 = tb*MT;
  const int tid = threadIdx.x;
  const int t = tmap[bn0 & (NN-1)];
  const int rg = tid >> 5, cg = tid & 31;
  const int r0 = rg*2;
  const int c0 = cg*4;
  {
    const float4* src = (const float4*)(S_ws + (size_t)bn0*64);
    ((float4*)sl)[tid] = src[tid];
  }
  /* per-type stats (types sorted: type t occupies n in [t*512, t*512+512)) */
  {
    float fs = 0.f, fss = 0.f;
    #pragma unroll 4
    for (int i = 0; i < 16; ++i) {
      const int e = i*256 + tid;
      const int b = e >> 9;
      const int n = t*512 + (e & 511);
      const float2 v = *(const float2*)&statp[((size_t)(b*NN + n))*2];
      fs += v.x; fss += v.y;
    }
    for (int o = 32; o > 0; o >>= 1) { fs += __shfl_down(fs, o); fss += __shfl_down(fss, o); }
    if ((tid & 63) == 0) { srd[(tid>>6)*2] = fs; srd[(tid>>6)*2+1] = fss; }
  }
  __syncthreads();
  if (tid == 0) {
    const float S1 = srd[0]+srd[2]+srd[4]+srd[6];
    const float S2 = srd[1]+srd[3]+srd[5]+srd[7];
    const float cnt = 512.0f * (float)BB * (float)NFEAT;
    const float mu = S1/cnt;
    const float var = (S2 - cnt*mu*mu)/(cnt - 1.0f);
    muSd[0] = mu; muSd[1] = sqrtf(fmaxf(var, 1e-20f));
  }
  __syncthreads();
  const float mu = muSd[0];
  const float inv_sd = 1.0f/muSd[1];
  #pragma unroll
  for (int i = 0; i < 4; ++i) {
    const int e = i*256 + tid;
    const int r = e >> 6, f = e & 63;
    const int p = f >> 2, q = f & 3;
    const float* Sr = &sl[r*64];
    float s = 0.f;
    #pragma unroll
    for (int a = 0; a < 4; ++a) s += Sr[p*4+a]*Sr[q*4+a];
    xb[f*PAD + r] = (s - mu)*inv_sd;
  }

  float acc[2][4], dh1r[2][4], wor[4];

  /* L0 */
  {
    const float* bp = b0 + t*HH;
    const float bj0 = bp[c0], bj1 = bp[c0+1], bj2 = bp[c0+2], bj3 = bp[c0+3];
    #pragma unroll
    for (int i = 0; i < 2; ++i) { acc[i][0]=bj0; acc[i][1]=bj1; acc[i][2]=bj2; acc[i][3]=bj3; }
  }
  GEMM128(W0 + (size_t)t*NFEAT*HH, 64, xb);
  __syncthreads();
  #pragma unroll
  for (int i = 0; i < 2; ++i)
    #pragma unroll
    for (int j = 0; j < 4; ++j) t0b[(c0+j)*PAD + r0+i] = ftanh(acc[i][j]);

  /* L1 */
  {
    const float* bp = b1 + t*HH;
    const float bj0 = bp[c0], bj1 = bp[c0+1], bj2 = bp[c0+2], bj3 = bp[c0+3];
    #pragma unroll
    for (int i = 0; i < 2; ++i) { acc[i][0]=bj0; acc[i][1]=bj1; acc[i][2]=bj2; acc[i][3]=bj3; }
  }
  GEMM128(W1 + (size_t)t*HH*HH, 128, t0b);
  __syncthreads();
  #pragma unroll
  for (int i = 0; i < 2; ++i)
    #pragma unroll
    for (int j = 0; j < 4; ++j)
      h1b[(c0+j)*PAD + r0+i] = ftanh(acc[i][j]) + t0b[(c0+j)*PAD + r0+i];

  /* L2 */
  {
    const float* bp = b2 + t*HH;
    const float bj0 = bp[c0], bj1 = bp[c0+1], bj2 = bp[c0+2], bj3 = bp[c0+3];
    #pragma unroll
    for (int i = 0; i < 2; ++i) { acc[i][0]=bj0; acc[i][1]=bj1; acc[i][2]=bj2; acc[i][3]=bj3; }
  }
  GEMM128(W2 + (size_t)t*HH*HH, 128, h1b);
  __syncthreads();

  #pragma unroll
  for (int j = 0; j < 4; ++j) wor[j] = Wout[t*HH + c0 + j];

  /* energy + dz2 */
  {
    float pr0 = 0.f, pr1 = 0.f;
    #pragma unroll
    for (int i = 0; i < 2; ++i)
      #pragma unroll
      for (int j = 0; j < 4; ++j) {
        const float t2 = ftanh(acc[i][j]);
        const float h2 = t2 + h1b[(c0+j)*PAD + r0+i];
        if (i == 0) pr0 += h2*wor[j]; else pr1 += h2*wor[j];
        dzb[(c0+j)*PAD + r0+i] = wor[j]*(1.0f - t2*t2);
      }
    for (int o = 16; o > 0; o >>= 1) {
      pr0 += __shfl_down(pr0, o, 32);
      pr1 += __shfl_down(pr1, o, 32);
    }
    if (cg == 0) { es[r0] = pr0; es[r0+1] = pr1; }
  }
  __syncthreads();
  if (tid < MT) out[OUT_EI + bn0 + tid] = es[tid] + bout[t];

  /* dh1 = wo + dz2 @ W2^T */
  #pragma unroll
  for (int i = 0; i < 2; ++i)
    #pragma unroll
    for (int j = 0; j < 4; ++j) acc[i][j] = wor[j];
  GEMM128(wt + WT2_OFF + (size_t)t*HH*HH, 128, dzb);
  #pragma unroll
  for (int i = 0; i < 2; ++i)
    #pragma unroll
    for (int j = 0; j < 4; ++j) dh1r[i][j] = acc[i][j];
  __syncthreads();
  #pragma unroll
  for (int i = 0; i < 2; ++i)
    #pragma unroll
    for (int j = 0; j < 4; ++j) {
      const float t1 = h1b[(c0+j)*PAD + r0+i] - t0b[(c0+j)*PAD + r0+i];
      dzb[(c0+j)*PAD + r0+i] = dh1r[i][j]*(1.0f - t1*t1);
    }
  /* dh0 = dh1 + dz1 @ W1^T */
  #pragma unroll
  for (int i = 0; i < 2; ++i)
    #pragma unroll
    for (int j = 0; j < 4; ++j) acc[i][j] = dh1r[i][j];
  GEMM128(wt + WT1_OFF + (size_t)t*HH*HH, 128, dzb);
  __syncthreads();
  #pragma unroll
  for (int i = 0; i < 2; ++i)
    #pragma unroll
    for (int j = 0; j < 4; ++j) {
      const float t0 = t0b[(c0+j)*PAD + r0+i];
      dzb[(c0+j)*PAD + r0+i] = acc[i][j]*(1.0f - t0*t0);
    }
  /* dx = dz0 @ W0^T */
  {
    float a2[2][2];
    a2[0][0]=0.f; a2[0][1]=0.f; a2[1][0]=0.f; a2[1][1]=0.f;
    const float* WT0t = wt + WT0_OFF + (size_t)t*HH*NFEAT;
    for (int kc = 0; kc < 128; kc += 32) {
      __syncthreads();
      { const float4* _s = (const float4*)(WT0t + kc*64);
        float4* _d = (float4*)bb;
        _d[tid] = _s[tid]; _d[tid+256] = _s[tid+256]; }
      __syncthreads();
      #pragma unroll 4
      for (int k = 0; k < 32; ++k) {
        const float2 av = *(const float2*)&dzb[(kc+k)*PAD + r0];
        const float2 bv = *(const float2*)&bb[k*64 + cg*2];
        a2[0][0] += av.x*bv.x; a2[0][1] += av.x*bv.y;
        a2[1][0] += av.y*bv.x; a2[1][1] += av.y*bv.y;
      }
    }
    #pragma unroll
    for (int i = 0; i < 2; ++i) {
      float2 v; v.x = a2[i][0]*inv_sd; v.y = a2[i][1]*inv_sd;
      *(float2*)&dfeat_ws[(size_t)(bn0 + r0 + i)*64 + cg*2] = v;
    }
  }
}

/* ---- backward pair kernel via E-factorization ---- */
__global__ __launch_bounds__(256) void k_bwd(
    const float* __restrict__ rvec,
    const int* __restrict__ tmap, const float* __restrict__ c_param,
    const float* __restrict__ S_ws, const float* __restrict__ dfeat_ws,
    float* __restrict__ dxp, float* __restrict__ dyp, float* __restrict__ dzp,
    float* __restrict__ virp, float* __restrict__ cf)
{
  __shared__ float rv[768];
  __shared__ float c_lds[256];
  __shared__ float S_lds[64];
  __shared__ float df_lds[64];
  __shared__ float dS[64];
  __shared__ float E[64];
  __shared__ float wred[4*12];
  const int bn = blockIdx.x;
  const int b = bn >> 10;
  const int n = bn & (NN-1);
  const int tid = threadIdx.x;
  const int ti = tmap[n];
  c_lds[tid] = c_param[ti*256 + tid];
  const float* rb = rvec + (size_t)bn*MM*3;
  rv[tid] = rb[tid]; rv[tid+256] = rb[tid+256]; rv[tid+512] = rb[tid+512];
  if (tid < 64) {
    S_lds[tid] = S_ws[(size_t)bn*64 + tid];
    df_lds[tid] = dfeat_ws[(size_t)bn*64 + tid];
  }
  __syncthreads();
  if (tid < 64) {
    const int i = tid >> 2, a = tid & 3;
    float v = 0.f;
    #pragma unroll
    for (int q = 0; q < 4; ++q) v += df_lds[i*4+q]*S_lds[q*4+a];
    if (i < 4)
      for (int p = 0; p < 16; ++p) v += df_lds[p*4+i]*S_lds[p*4+a];
    dS[tid] = v;
  }
  __syncthreads();
  if (tid < 64) {
    const int tj = tid >> 5, rem = tid & 31;
    const int a = rem >> 3, k = rem & 7;
    float e = 0.f;
    #pragma unroll
    for (int p = 0; p < 16; ++p) e += dS[p*4+a]*c_lds[tj*128 + p*8 + k];
    E[tj*32 + a*8 + k] = e;
  }
  __syncthreads();
  const int m = tid;
  const float x = rv[3*m], y = rv[3*m+1], z = rv[3*m+2];
  const float r = sqrtf(x*x+y*y+z*z);
  const float inv_r = 1.0f/r;
  const float ux = x*inv_r, uy = y*inv_r, uz = z*inv_r;
  float u = 2.0f*(r - RMINf)/SPANf - 1.0f;
  u = fminf(fmaxf(u, -1.0f), 1.0f);
  const float arg = PIf*(r - RMINf)/SPANf;
  float sarg, carg;
  __sincosf(arg, &sarg, &carg);
  const float fc = 0.5f*(carg + 1.0f);
  const float dfc = -0.5f*(PIf/SPANf)*sarg;
  float T[BETA], dT[BETA];
  T[0]=1.f; T[1]=u; dT[0]=0.f; dT[1]=1.f;
  #pragma unroll
  for (int k=2;k<BETA;++k){
    T[k]  = 2.f*u*T[k-1] - T[k-2];
    dT[k] = 2.f*T[k-1] + 2.f*u*dT[k-1] - dT[k-2];
  }
  const float* Et = &E[(m >> 7)*32];
  float ta[4], tda[4];
  #pragma unroll
  for (int a = 0; a < 4; ++a) {
    float s = 0.f, sd2 = 0.f;
    #pragma unroll
    for (int k = 0; k < 8; ++k) {
      const float e = Et[a*8 + k];
      s   += T[k]*e;
      sd2 += dT[k]*e;
    }
    ta[a] = s; tda[a] = sd2;
  }
  const float dudr = 2.0f/SPANf;
  const float invM = 1.0f/(float)MM;
  float A = dfc*(ta[0] + ux*ta[1] + uy*ta[2] + uz*ta[3])
          + fc*dudr*(tda[0] + ux*tda[1] + uy*tda[2] + uz*tda[3]);
  float dq1 = fc*ta[1], dq2 = fc*ta[2], dq3 = fc*ta[3];
  A *= invM; dq1 *= invM; dq2 *= invM; dq3 *= invM;
  const float dqu = dq1*ux + dq2*uy + dq3*uz;
  const float d0 = A*ux + (dq1 - dqu*ux)*inv_r;
  const float d1 = A*uy + (dq2 - dqu*uy)*inv_r;
  const float d2 = A*uz + (dq3 - dqu*uz)*inv_r;
  const size_t gp = (size_t)bn*MM + m;
  dxp[gp] = d0; dyp[gp] = d1; dzp[gp] = d2;
  float red[12];
  red[0]=d0;    red[1]=d1;    red[2]=d2;
  red[3]=-x*d0; red[4]=-x*d1; red[5]=-x*d2;
  red[6]=-y*d0; red[7]=-y*d1; red[8]=-y*d2;
  red[9]=-z*d0; red[10]=-z*d1; red[11]=-z*d2;
  #pragma unroll
  for (int i=0;i<12;++i){
    float v = red[i];
    for (int o=32;o>0;o>>=1) v += __shfl_down(v,o);
    if ((tid & 63) == 0) wred[(tid>>6)*12 + i] = v;
  }
  __syncthreads();
  if (tid < 12) {
    const float v = wred[tid] + wred[12+tid] + wred[24+tid] + wred[36+tid];
    if (tid < 3) cf[((size_t)b*NN + n)*3 + tid] = v;
    else virp[(size_t)bn*9 + (tid-3)] = v;
  }
}

__global__ __launch_bounds__(256) void k_scatter(
    const int* __restrict__ nlist,
    const float* __restrict__ dxp, const float* __restrict__ dyp,
    const float* __restrict__ dzp, float* __restrict__ fpart_ws)
{
  __shared__ float fpart[F3];
  const int tid = threadIdx.x;
  const int blk = blockIdx.x;
  const int b = blk >> 5;
  const int g = blk & (NGROUP-1);
  for (int i = tid; i < F3; i += 256) fpart[i] = 0.f;
  __syncthreads();
  const size_t base = (size_t)b*PAIRS_PER_BATCH + (size_t)g*PAIRS_PER_GROUP;
  for (int i = 0; i < PAIRS_PER_GROUP/256; ++i) {
    const size_t gp = base + i*256 + tid;
    const int nl = nlist[gp];
    if (nl > 0) {
      const int j = nl - 1;
      atomicAdd(&fpart[j*3+0], -dxp[gp]);
      atomicAdd(&fpart[j*3+1], -dyp[gp]);
      atomicAdd(&fpart[j*3+2], -dzp[gp]);
    }
  }
  __syncthreads();
  float* dst = fpart_ws + (size_t)blk*F3;
  for (int i = tid; i < F3; i += 256) dst[i] = fpart[i];
}

/* blocks 0..101: force (scatter partials + center from cf, pure write)
   blocks 102..173: virial (72 blocks, one per (b,component))
   blocks 174..181: Etot (8 blocks, sum Ei) */
__global__ __launch_bounds__(256) void k_reduce(
    const float* __restrict__ fpart_ws, const float* __restrict__ virp,
    const float* __restrict__ cf, float* __restrict__ out)
{
  __shared__ float red[4];
  const int tid = threadIdx.x;
  const int blk = blockIdx.x;
  if (blk < 102) {
    const int e = blk*256 + tid;       /* e < 26112 == BB*F3 exactly */
    const int b = e / F3;
    const int i = e - b*F3;
    float s = 0.f;
    for (int g = 0; g < NGROUP; ++g)
      s += fpart_ws[((size_t)(b*NGROUP + g))*F3 + i];
    const int n = i / 3;
    if (n < NN) s += cf[((size_t)b*NN + n)*3 + (i - n*3)];
    out[OUT_FORCE + e] = s;
    return;
  }
  float v = 0.f;
  if (blk < 174) {
    const int vb = blk - 102;
    const int b = vb / 9, c = vb - (vb/9)*9;
    #pragma unroll
    for (int k = 0; k < 4; ++k)
      v += virp[((size_t)b*NN + (k*256 + tid))*9 + c];
  } else {
    const int b = blk - 174;
    #pragma unroll
    for (int k = 0; k < 4; ++k)
      v += out[OUT_EI + b*NN + k*256 + tid];
  }
  for (int o = 32; o > 0; o >>= 1) v += __shfl_down(v, o);
  if ((tid & 63) == 0) red[tid >> 6] = v;
  __syncthreads();
  if (tid == 0) {
    const float s = red[0] + red[1] + red[2] + red[3];
    if (blk < 174) out[OUT_VIR + (blk - 102)] = s;
    else out[blk - 174] = s;
  }
}

extern "C" void kernel_launch(void* const* d_in, const int* in_sizes, int n_in,
                              void* d_out, int out_size, void* d_ws, size_t ws_size,
                              hipStream_t stream)
{
  const int*   nlist = (const int*)d_in[0];
  const int*   tmap  = (const int*)d_in[1];
  const float* rvec  = (const float*)d_in[2];
  const float* cpar  = (const float*)d_in[3];
  const float* W0 = (const float*)d_in[4];
  const float* b0 = (const float*)d_in[5];
  const float* W1 = (const float*)d_in[6];
  const float* b1 = (const float*)d_in[7];
  const float* W2 = (const float*)d_in[8];
  const float* b2 = (const float*)d_in[9];
  const float* Wout = (const float*)d_in[10];
  const float* bout = (const float*)d_in[11];
  float* out = (float*)d_out;
  float* ws = (float*)d_ws;
  float* S_ws   = ws + WS_S;
  float* df_ws  = ws + WS_DF;
  float* dxp    = ws + WS_DX;
  float* dyp    = ws + WS_DY;
  float* dzp    = ws + WS_DZ;
  float* statp  = ws + WS_STATP;
  float* virp   = ws + WS_VIRP;
  float* fpartw = ws + WS_FPART;
  float* wt     = ws + WS_WT;
  float* cf     = ws + WS_CF;    /* aliases wt (disjoint lifetimes) */

  k_feat <<<BB*NN + 320, 256, 0, stream>>>(rvec, tmap, cpar, S_ws, statp,
                                           W0, W1, W2, wt);
  k_mlp  <<<(BB*NN)/MT, 256, 0, stream>>>(S_ws, tmap, statp, wt,
                                     W0,b0,W1,b1,W2,b2,Wout,bout, df_ws, out);
  k_bwd  <<<BB*NN, 256, 0, stream>>>(rvec, tmap, cpar, S_ws, df_ws,
                                     dxp, dyp, dzp, virp, cf);
  k_scatter<<<BB*NGROUP, 256, 0, stream>>>(nlist, dxp, dyp, dzp, fpartw);
  k_reduce <<<182, 256, 0, stream>>>(fpartw, virp, cf, out);
}

// Round 7
// 211.378 us; speedup vs baseline: 3.9713x; 1.0490x over previous
//
#include <hip/hip_runtime.h>
#include <math.h>

#define BB 8
#define NN 1024
#define MM 256
#define BETA 8
#define M1 16
#define NFEAT 64
#define HH 128
#define NTOT 1088   /* N + NGHOST */
#define F3 (NTOT*3) /* 3264 */
#define RMINf 0.5f
#define SPANf 5.5f
#define PIf 3.14159265358979323846f

#define OUT_EI 8
#define OUT_FORCE 8200          /* 8 + 8192 */
#define OUT_VIR 34312           /* 8200 + 8*1088*3 */

#define NG2 64                  /* scatter/bwd groups per batch */
#define AT2 (NN/NG2)            /* 16 atoms per fused block */

#define MT 16                   /* atoms per MLP tile */
#define PAD 18                  /* activation LDS leading-dim pad (b64-aligned) */

/* workspace float offsets */
#define WS_S     0
#define WS_DF    (WS_S + 8192*64)
#define WS_FP    (WS_DF + 8192*64)       /* fpart partials: 512*F3 = 1671168 <= 2097152 */
#define WS_STATP (WS_FP + 8192*256)
#define WS_MUSTD (WS_STATP + 8192*2)
#define WS_VIRP  (WS_MUSTD + 4)          /* 512*9 */
#define WS_WT    (WS_VIRP + 8192*9)
#define WT0_OFF  0
#define WT1_OFF  16384
#define WT2_OFF  49152

__device__ __forceinline__ float ftanh(float x) {
  const float e = __expf(2.0f*x);
  return 1.0f - 2.0f/(e + 1.0f);
}

/* ---- features via U-factorization + fused weight transpose blocks ---- */
__global__ __launch_bounds__(256) void k_feat(
    const float* __restrict__ rvec, const int* __restrict__ tmap,
    const float* __restrict__ c_param, float* __restrict__ S_ws,
    float* __restrict__ statp,
    const float* __restrict__ W0, const float* __restrict__ W1,
    const float* __restrict__ W2, float* __restrict__ wt)
{
  __shared__ float rv[768];
  __shared__ float c_lds[256];
  __shared__ float prod[256*33];
  __shared__ float part[8*32];
  __shared__ float U[2*32];
  __shared__ float S_lds[64];
  const int tid = threadIdx.x;
  if (blockIdx.x >= BB*NN) {
    const int idx = (blockIdx.x - BB*NN)*256 + tid;
    if (idx < 16384) {
      const int t = idx >> 13, rem = idx & 8191;
      const int j = rem >> 6, f = rem & 63;
      wt[WT0_OFF + idx] = W0[t*8192 + f*128 + j];
    } else if (idx < 49152) {
      const int i = idx - 16384;
      const int t = i >> 14, rem = i & 16383;
      const int j = rem >> 7, f = rem & 127;
      wt[WT1_OFF + i] = W1[t*16384 + f*128 + j];
    } else if (idx < 81920) {
      const int i = idx - 49152;
      const int t = i >> 14, rem = i & 16383;
      const int j = rem >> 7, f = rem & 127;
      wt[WT2_OFF + i] = W2[t*16384 + f*128 + j];
    }
    return;
  }
  const int bn = blockIdx.x;
  const int n = bn & (NN-1);
  const int ti = tmap[n];
  c_lds[tid] = c_param[ti*256 + tid];
  const float* rb = rvec + (size_t)bn*MM*3;
  rv[tid] = rb[tid]; rv[tid+256] = rb[tid+256]; rv[tid+512] = rb[tid+512];
  __syncthreads();
  const int m = tid;
  const float x = rv[3*m], y = rv[3*m+1], z = rv[3*m+2];
  const float r = sqrtf(x*x + y*y + z*z);
  const float inv_r = 1.0f / r;
  const float ux = x*inv_r, uy = y*inv_r, uz = z*inv_r;
  float u = 2.0f*(r - RMINf)/SPANf - 1.0f;
  u = fminf(fmaxf(u, -1.0f), 1.0f);
  const float fc = 0.5f*(__cosf(PIf*(r - RMINf)/SPANf) + 1.0f);
  float T[BETA];
  T[0] = 1.0f; T[1] = u;
  #pragma unroll
  for (int k = 2; k < BETA; ++k) T[k] = 2.0f*u*T[k-1] - T[k-2];
  float* pr = &prod[m*33];
  #pragma unroll
  for (int k = 0; k < BETA; ++k) {
    const float ft = fc*T[k];
    pr[k*4+0] = ft;
    pr[k*4+1] = ft*ux;
    pr[k*4+2] = ft*uy;
    pr[k*4+3] = ft*uz;
  }
  __syncthreads();
  {
    const int c = tid & 31, oct = tid >> 5;
    const int m0 = oct*32;
    float s = 0.f;
    #pragma unroll 8
    for (int i = 0; i < 32; ++i) s += prod[(m0+i)*33 + c];
    part[oct*32 + c] = s;
  }
  __syncthreads();
  if (tid < 64) {
    const int tj = tid >> 5, c = tid & 31;
    U[tid] = part[(tj*4+0)*32+c] + part[(tj*4+1)*32+c]
           + part[(tj*4+2)*32+c] + part[(tj*4+3)*32+c];
  }
  __syncthreads();
  if (tid < 64) {
    const int p = tid >> 2, a = tid & 3;
    float s = 0.f;
    #pragma unroll
    for (int tj = 0; tj < 2; ++tj)
      #pragma unroll
      for (int k = 0; k < 8; ++k)
        s += c_lds[tj*128 + p*8 + k] * U[tj*32 + k*4 + a];
    s *= (1.0f/(float)MM);
    S_lds[tid] = s;
    S_ws[(size_t)bn*64 + tid] = s;
  }
  __syncthreads();
  if (tid < 64) {
    const int p = tid >> 2, q = tid & 3;
    float f = 0.f;
    #pragma unroll
    for (int a = 0; a < 4; ++a) f += S_lds[p*4+a]*S_lds[q*4+a];
    float fs = f, fss = f*f;
    for (int o = 32; o > 0; o >>= 1) { fs += __shfl_down(fs, o); fss += __shfl_down(fss, o); }
    if (tid == 0) { statp[bn*2+0] = fs; statp[bn*2+1] = fss; }
  }
}

/* ---- tiled MLP (round-5 GEMM core, proven no-spill) + in-block stats ---- */
#define GEMM128(WPTR, K, ABUF) \
  for (int kc = 0; kc < (K); kc += 32) { \
    __syncthreads(); \
    { const float4* _s = (const float4*)((WPTR) + kc*128); \
      float4* _d = (float4*)bb; \
      _d[tid] = _s[tid]; _d[tid+256] = _s[tid+256]; \
      _d[tid+512] = _s[tid+512]; _d[tid+768] = _s[tid+768]; } \
    __syncthreads(); \
    _Pragma("unroll 4") \
    for (int k = 0; k < 32; ++k) { \
      const float2 av = *(const float2*)&(ABUF)[(kc+k)*PAD + r0]; \
      const float4 bv = *(const float4*)&bb[k*128 + c0]; \
      acc[0][0] += av.x*bv.x; acc[0][1] += av.x*bv.y; acc[0][2] += av.x*bv.z; acc[0][3] += av.x*bv.w; \
      acc[1][0] += av.y*bv.x; acc[1][1] += av.y*bv.y; acc[1][2] += av.y*bv.z; acc[1][3] += av.y*bv.w; \
    } \
  }

__global__ __launch_bounds__(256, 3) void k_mlp(
    const float* __restrict__ S_ws, const int* __restrict__ tmap,
    const float* __restrict__ statp, const float* __restrict__ wt,
    const float* __restrict__ W0, const float* __restrict__ b0,
    const float* __restrict__ W1, const float* __restrict__ b1,
    const float* __restrict__ W2, const float* __restrict__ b2,
    const float* __restrict__ Wout, const float* __restrict__ bout,
    float* __restrict__ dfeat_ws, float* __restrict__ out)
{
  __shared__ float xb[64*PAD];
  __shared__ float t0b[128*PAD];
  __shared__ float h1b[128*PAD];
  __shared__ float dzb[128*PAD];
  __shared__ float bb[32*128];
  __shared__ float sl[MT*64];
  __shared__ float es[MT];
  __shared__ float srd[8];
  __shared__ float muSd[2];
  const int tb = blockIdx.x;
  const int bn0 = tb*MT;
  const int tid = threadIdx.x;
  const int t = tmap[bn0 & (NN-1)];
  const int rg = tid >> 5, cg = tid & 31;
  const int r0 = rg*2;
  const int c0 = cg*4;
  {
    const float4* src = (const float4*)(S_ws + (size_t)bn0*64);
    ((float4*)sl)[tid] = src[tid];
  }
  {
    float fs = 0.f, fss = 0.f;
    #pragma unroll 4
    for (int i = 0; i < 16; ++i) {
      const int e = i*256 + tid;
      const int b = e >> 9;
      const int n = t*512 + (e & 511);
      const float2 v = *(const float2*)&statp[((size_t)(b*NN + n))*2];
      fs += v.x; fss += v.y;
    }
    for (int o = 32; o > 0; o >>= 1) { fs += __shfl_down(fs, o); fss += __shfl_down(fss, o); }
    if ((tid & 63) == 0) { srd[(tid>>6)*2] = fs; srd[(tid>>6)*2+1] = fss; }
  }
  __syncthreads();
  if (tid == 0) {
    const float S1 = srd[0]+srd[2]+srd[4]+srd[6];
    const float S2 = srd[1]+srd[3]+srd[5]+srd[7];
    const float cnt = 512.0f * (float)BB * (float)NFEAT;
    const float mu = S1/cnt;
    const float var = (S2 - cnt*mu*mu)/(cnt - 1.0f);
    muSd[0] = mu; muSd[1] = sqrtf(fmaxf(var, 1e-20f));
  }
  __syncthreads();
  const float mu = muSd[0];
  const float inv_sd = 1.0f/muSd[1];
  #pragma unroll
  for (int i = 0; i < 4; ++i) {
    const int e = i*256 + tid;
    const int r = e >> 6, f = e & 63;
    const int p = f >> 2, q = f & 3;
    const float* Sr = &sl[r*64];
    float s = 0.f;
    #pragma unroll
    for (int a = 0; a < 4; ++a) s += Sr[p*4+a]*Sr[q*4+a];
    xb[f*PAD + r] = (s - mu)*inv_sd;
  }

  float acc[2][4], dh1r[2][4], wor[4];

  /* L0 */
  {
    const float* bp = b0 + t*HH;
    const float bj0 = bp[c0], bj1 = bp[c0+1], bj2 = bp[c0+2], bj3 = bp[c0+3];
    #pragma unroll
    for (int i = 0; i < 2; ++i) { acc[i][0]=bj0; acc[i][1]=bj1; acc[i][2]=bj2; acc[i][3]=bj3; }
  }
  GEMM128(W0 + (size_t)t*NFEAT*HH, 64, xb);
  __syncthreads();
  #pragma unroll
  for (int i = 0; i < 2; ++i)
    #pragma unroll
    for (int j = 0; j < 4; ++j) t0b[(c0+j)*PAD + r0+i] = ftanh(acc[i][j]);

  /* L1 */
  {
    const float* bp = b1 + t*HH;
    const float bj0 = bp[c0], bj1 = bp[c0+1], bj2 = bp[c0+2], bj3 = bp[c0+3];
    #pragma unroll
    for (int i = 0; i < 2; ++i) { acc[i][0]=bj0; acc[i][1]=bj1; acc[i][2]=bj2; acc[i][3]=bj3; }
  }
  GEMM128(W1 + (size_t)t*HH*HH, 128, t0b);
  __syncthreads();
  #pragma unroll
  for (int i = 0; i < 2; ++i)
    #pragma unroll
    for (int j = 0; j < 4; ++j)
      h1b[(c0+j)*PAD + r0+i] = ftanh(acc[i][j]) + t0b[(c0+j)*PAD + r0+i];

  /* L2 */
  {
    const float* bp = b2 + t*HH;
    const float bj0 = bp[c0], bj1 = bp[c0+1], bj2 = bp[c0+2], bj3 = bp[c0+3];
    #pragma unroll
    for (int i = 0; i < 2; ++i) { acc[i][0]=bj0; acc[i][1]=bj1; acc[i][2]=bj2; acc[i][3]=bj3; }
  }
  GEMM128(W2 + (size_t)t*HH*HH, 128, h1b);
  __syncthreads();

  #pragma unroll
  for (int j = 0; j < 4; ++j) wor[j] = Wout[t*HH + c0 + j];

  /* energy + dz2 */
  {
    float pr0 = 0.f, pr1 = 0.f;
    #pragma unroll
    for (int i = 0; i < 2; ++i)
      #pragma unroll
      for (int j = 0; j < 4; ++j) {
        const float t2 = ftanh(acc[i][j]);
        const float h2 = t2 + h1b[(c0+j)*PAD + r0+i];
        if (i == 0) pr0 += h2*wor[j]; else pr1 += h2*wor[j];
        dzb[(c0+j)*PAD + r0+i] = wor[j]*(1.0f - t2*t2);
      }
    for (int o = 16; o > 0; o >>= 1) {
      pr0 += __shfl_down(pr0, o, 32);
      pr1 += __shfl_down(pr1, o, 32);
    }
    if (cg == 0) { es[r0] = pr0; es[r0+1] = pr1; }
  }
  __syncthreads();
  if (tid < MT) out[OUT_EI + bn0 + tid] = es[tid] + bout[t];

  /* dh1 = wo + dz2 @ W2^T */
  #pragma unroll
  for (int i = 0; i < 2; ++i)
    #pragma unroll
    for (int j = 0; j < 4; ++j) acc[i][j] = wor[j];
  GEMM128(wt + WT2_OFF + (size_t)t*HH*HH, 128, dzb);
  #pragma unroll
  for (int i = 0; i < 2; ++i)
    #pragma unroll
    for (int j = 0; j < 4; ++j) dh1r[i][j] = acc[i][j];
  __syncthreads();
  #pragma unroll
  for (int i = 0; i < 2; ++i)
    #pragma unroll
    for (int j = 0; j < 4; ++j) {
      const float t1 = h1b[(c0+j)*PAD + r0+i] - t0b[(c0+j)*PAD + r0+i];
      dzb[(c0+j)*PAD + r0+i] = dh1r[i][j]*(1.0f - t1*t1);
    }
  /* dh0 = dh1 + dz1 @ W1^T */
  #pragma unroll
  for (int i = 0; i < 2; ++i)
    #pragma unroll
    for (int j = 0; j < 4; ++j) acc[i][j] = dh1r[i][j];
  GEMM128(wt + WT1_OFF + (size_t)t*HH*HH, 128, dzb);
  __syncthreads();
  #pragma unroll
  for (int i = 0; i < 2; ++i)
    #pragma unroll
    for (int j = 0; j < 4; ++j) {
      const float t0 = t0b[(c0+j)*PAD + r0+i];
      dzb[(c0+j)*PAD + r0+i] = acc[i][j]*(1.0f - t0*t0);
    }
  /* dx = dz0 @ W0^T */
  {
    float a2[2][2];
    a2[0][0]=0.f; a2[0][1]=0.f; a2[1][0]=0.f; a2[1][1]=0.f;
    const float* WT0t = wt + WT0_OFF + (size_t)t*HH*NFEAT;
    for (int kc = 0; kc < 128; kc += 32) {
      __syncthreads();
      { const float4* _s = (const float4*)(WT0t + kc*64);
        float4* _d = (float4*)bb;
        _d[tid] = _s[tid]; _d[tid+256] = _s[tid+256]; }
      __syncthreads();
      #pragma unroll 4
      for (int k = 0; k < 32; ++k) {
        const float2 av = *(const float2*)&dzb[(kc+k)*PAD + r0];
        const float2 bv = *(const float2*)&bb[k*64 + cg*2];
        a2[0][0] += av.x*bv.x; a2[0][1] += av.x*bv.y;
        a2[1][0] += av.y*bv.x; a2[1][1] += av.y*bv.y;
      }
    }
    #pragma unroll
    for (int i = 0; i < 2; ++i) {
      float2 v; v.x = a2[i][0]*inv_sd; v.y = a2[i][1]*inv_sd;
      *(float2*)&dfeat_ws[(size_t)(bn0 + r0 + i)*64 + cg*2] = v;
    }
  }
}

/* ---- fused backward pair + scatter kernel ----
   512 blocks = 8 batches x 64 groups of 16 atoms. Per block:
   stage S/df -> dS -> E in LDS, loop 16 atoms x 256 pairs computing dEdr
   inline, scatter neighbors into private LDS fpart (atomics), center force
   via wave reductions folded into fpart, virial in registers. */
__global__ __launch_bounds__(256) void k_bwdsc(
    const float* __restrict__ rvec, const int* __restrict__ nlist,
    const int* __restrict__ tmap, const float* __restrict__ c_param,
    const float* __restrict__ S_ws, const float* __restrict__ dfeat_ws,
    float* __restrict__ fpart_ws, float* __restrict__ virp)
{
  __shared__ float c_lds[256];
  __shared__ float Sb[AT2*64];
  __shared__ float Db[AT2*64];
  __shared__ float dSb[AT2*64];
  __shared__ float Eb[AT2*64];
  __shared__ float fpart[F3];
  __shared__ float wredc[AT2*4*3];
  __shared__ float vred[4*9];
  const int blk = blockIdx.x;          /* b*NG2 + g */
  const int b = blk >> 6;
  const int g = blk & (NG2-1);
  const int n0 = g*AT2;
  const int tid = threadIdx.x;
  const int ti = tmap[n0];             /* type uniform across group (16|512) */
  c_lds[tid] = c_param[ti*256 + tid];
  {
    const float4* s4 = (const float4*)(S_ws + ((size_t)b*NN + n0)*64);
    const float4* d4 = (const float4*)(dfeat_ws + ((size_t)b*NN + n0)*64);
    ((float4*)Sb)[tid] = s4[tid];
    ((float4*)Db)[tid] = d4[tid];
  }
  for (int i = tid; i < F3; i += 256) fpart[i] = 0.f;
  __syncthreads();
  /* dS[at][i][a] = sum_q df[i][q] S[q][a] + (i<4) sum_p df[p][i] S[p][a] */
  #pragma unroll
  for (int it = 0; it < 4; ++it) {
    const int idx = it*256 + tid;
    const int at = idx >> 6, f = idx & 63;
    const int i = f >> 2, a = f & 3;
    const float* Sr = &Sb[at*64];
    const float* Dr = &Db[at*64];
    float v = 0.f;
    #pragma unroll
    for (int q = 0; q < 4; ++q) v += Dr[i*4+q]*Sr[q*4+a];
    if (i < 4)
      for (int p = 0; p < 16; ++p) v += Dr[p*4+i]*Sr[p*4+a];
    dSb[idx] = v;
  }
  __syncthreads();
  /* E[at][tj][a][k] = sum_p dS[at][p][a] c[tj][p][k] */
  #pragma unroll
  for (int it = 0; it < 4; ++it) {
    const int idx = it*256 + tid;
    const int at = idx >> 6, rem = idx & 63;
    const int tj = rem >> 5, a = (rem >> 3) & 3, k = rem & 7;
    float e = 0.f;
    #pragma unroll
    for (int p = 0; p < 16; ++p) e += dSb[at*64 + p*4 + a]*c_lds[tj*128 + p*8 + k];
    Eb[idx] = e;
  }
  __syncthreads();

  float vir[9];
  #pragma unroll
  for (int i = 0; i < 9; ++i) vir[i] = 0.f;
  const int wave = tid >> 6, lane = tid & 63;
  const int tjm = tid >> 7;            /* neighbor-type half: m>>7 */
  const float dudr = 2.0f/SPANf;
  const float invM = 1.0f/(float)MM;

  const size_t rowbase = ((size_t)b*NN + n0)*MM;
  float px, py, pz; int pnl;
  {
    const float* rp = rvec + (rowbase + tid)*3;
    px = rp[0]; py = rp[1]; pz = rp[2];
    pnl = nlist[rowbase + tid];
  }
  for (int a = 0; a < AT2; ++a) {
    const float x = px, y = py, z = pz; const int nl = pnl;
    if (a + 1 < AT2) {
      const float* rp = rvec + (rowbase + (size_t)(a+1)*MM + tid)*3;
      px = rp[0]; py = rp[1]; pz = rp[2];
      pnl = nlist[rowbase + (size_t)(a+1)*MM + tid];
    }
    const float r = sqrtf(x*x + y*y + z*z);
    const float inv_r = 1.0f/r;
    const float ux = x*inv_r, uy = y*inv_r, uz = z*inv_r;
    float u = 2.0f*(r - RMINf)/SPANf - 1.0f;
    u = fminf(fmaxf(u, -1.0f), 1.0f);
    const float arg = PIf*(r - RMINf)/SPANf;
    float sarg, carg;
    __sincosf(arg, &sarg, &carg);
    const float fc = 0.5f*(carg + 1.0f);
    const float dfc = -0.5f*(PIf/SPANf)*sarg;
    float T[BETA], dT[BETA];
    T[0]=1.f; T[1]=u; dT[0]=0.f; dT[1]=1.f;
    #pragma unroll
    for (int k = 2; k < BETA; ++k) {
      T[k]  = 2.f*u*T[k-1] - T[k-2];
      dT[k] = 2.f*T[k-1] + 2.f*u*dT[k-1] - dT[k-2];
    }
    const float* Et = &Eb[a*64 + tjm*32];
    float ta[4], tda[4];
    #pragma unroll
    for (int aa = 0; aa < 4; ++aa) {
      float s = 0.f, sd2 = 0.f;
      #pragma unroll
      for (int k = 0; k < 8; ++k) {
        const float e = Et[aa*8 + k];
        s   += T[k]*e;
        sd2 += dT[k]*e;
      }
      ta[aa] = s; tda[aa] = sd2;
    }
    float A = dfc*(ta[0] + ux*ta[1] + uy*ta[2] + uz*ta[3])
            + fc*dudr*(tda[0] + ux*tda[1] + uy*tda[2] + uz*tda[3]);
    float dq1 = fc*ta[1], dq2 = fc*ta[2], dq3 = fc*ta[3];
    A *= invM; dq1 *= invM; dq2 *= invM; dq3 *= invM;
    const float dqu = dq1*ux + dq2*uy + dq3*uz;
    const float d0 = A*ux + (dq1 - dqu*ux)*inv_r;
    const float d1 = A*uy + (dq2 - dqu*uy)*inv_r;
    const float d2 = A*uz + (dq3 - dqu*uz)*inv_r;
    if (nl > 0) {
      const int j = nl - 1;
      atomicAdd(&fpart[j*3+0], -d0);
      atomicAdd(&fpart[j*3+1], -d1);
      atomicAdd(&fpart[j*3+2], -d2);
    }
    vir[0] -= x*d0; vir[1] -= x*d1; vir[2] -= x*d2;
    vir[3] -= y*d0; vir[4] -= y*d1; vir[5] -= y*d2;
    vir[6] -= z*d0; vir[7] -= z*d1; vir[8] -= z*d2;
    float r0 = d0, r1 = d1, r2 = d2;
    for (int o = 32; o > 0; o >>= 1) {
      r0 += __shfl_down(r0, o);
      r1 += __shfl_down(r1, o);
      r2 += __shfl_down(r2, o);
    }
    if (lane == 0) {
      wredc[(a*4 + wave)*3 + 0] = r0;
      wredc[(a*4 + wave)*3 + 1] = r1;
      wredc[(a*4 + wave)*3 + 2] = r2;
    }
  }
  #pragma unroll
  for (int i = 0; i < 9; ++i) {
    float v = vir[i];
    for (int o = 32; o > 0; o >>= 1) v += __shfl_down(v, o);
    if (lane == 0) vred[wave*9 + i] = v;
  }
  __syncthreads();
  if (tid < AT2*3) {
    const int at = tid/3, c = tid - at*3;
    const float v = wredc[(at*4+0)*3+c] + wredc[(at*4+1)*3+c]
                  + wredc[(at*4+2)*3+c] + wredc[(at*4+3)*3+c];
    atomicAdd(&fpart[(n0+at)*3 + c], v);
  }
  if (tid >= 64 && tid < 73) {
    const int i = tid - 64;
    virp[(size_t)blk*9 + i] = vred[i] + vred[9+i] + vred[18+i] + vred[27+i];
  }
  __syncthreads();
  float* dst = fpart_ws + (size_t)blk*F3;
  for (int i = tid; i < F3; i += 256) dst[i] = fpart[i];
}

/* blocks 0..101: force (sum 64 group partials, pure write)
   blocks 102..109: virial per batch   blocks 110..117: Etot per batch */
__global__ __launch_bounds__(256) void k_reduce(
    const float* __restrict__ fpart_ws, const float* __restrict__ virp,
    float* __restrict__ out)
{
  __shared__ float red[4];
  const int tid = threadIdx.x;
  const int blk = blockIdx.x;
  if (blk < 102) {
    const int e = blk*256 + tid;       /* e < 26112 == BB*F3 exactly */
    const int b = e / F3;
    const int i = e - b*F3;
    float s = 0.f;
    for (int g = 0; g < NG2; ++g)
      s += fpart_ws[((size_t)(b*NG2 + g))*F3 + i];
    out[OUT_FORCE + e] = s;
    return;
  }
  const int wave = tid >> 6, lane = tid & 63;
  if (blk < 110) {
    const int b = blk - 102;
    for (int pc = 0; pc < 3; ++pc) {
      const int c = pc*4 + wave;
      if (c < 9) {
        float v = virp[((size_t)(b*NG2 + lane))*9 + c];
        for (int o = 32; o > 0; o >>= 1) v += __shfl_down(v, o);
        if (lane == 0) out[OUT_VIR + b*9 + c] = v;
      }
    }
    return;
  }
  const int b = blk - 110;
  float v = 0.f;
  #pragma unroll
  for (int k = 0; k < 4; ++k) v += out[OUT_EI + b*NN + k*256 + tid];
  for (int o = 32; o > 0; o >>= 1) v += __shfl_down(v, o);
  if ((tid & 63) == 0) red[tid >> 6] = v;
  __syncthreads();
  if (tid == 0) out[b] = red[0] + red[1] + red[2] + red[3];
}

extern "C" void kernel_launch(void* const* d_in, const int* in_sizes, int n_in,
                              void* d_out, int out_size, void* d_ws, size_t ws_size,
                              hipStream_t stream)
{
  const int*   nlist = (const int*)d_in[0];
  const int*   tmap  = (const int*)d_in[1];
  const float* rvec  = (const float*)d_in[2];
  const float* cpar  = (const float*)d_in[3];
  const float* W0 = (const float*)d_in[4];
  const float* b0 = (const float*)d_in[5];
  const float* W1 = (const float*)d_in[6];
  const float* b1 = (const float*)d_in[7];
  const float* W2 = (const float*)d_in[8];
  const float* b2 = (const float*)d_in[9];
  const float* Wout = (const float*)d_in[10];
  const float* bout = (const float*)d_in[11];
  float* out = (float*)d_out;
  float* ws = (float*)d_ws;
  float* S_ws   = ws + WS_S;
  float* df_ws  = ws + WS_DF;
  float* fpartw = ws + WS_FP;
  float* statp  = ws + WS_STATP;
  float* virp   = ws + WS_VIRP;
  float* wt     = ws + WS_WT;

  k_feat <<<BB*NN + 320, 256, 0, stream>>>(rvec, tmap, cpar, S_ws, statp,
                                           W0, W1, W2, wt);
  k_mlp  <<<(BB*NN)/MT, 256, 0, stream>>>(S_ws, tmap, statp, wt,
                                     W0,b0,W1,b1,W2,b2,Wout,bout, df_ws, out);
  k_bwdsc<<<BB*NG2, 256, 0, stream>>>(rvec, nlist, tmap, cpar, S_ws, df_ws,
                                      fpartw, virp);
  k_reduce<<<118, 256, 0, stream>>>(fpartw, virp, out);
}

// Round 8
// 210.205 us; speedup vs baseline: 3.9935x; 1.0056x over previous
//
#include <hip/hip_runtime.h>
#include <math.h>

#define BB 8
#define NN 1024
#define MM 256
#define BETA 8
#define M1 16
#define NFEAT 64
#define HH 128
#define NTOT 1088   /* N + NGHOST */
#define F3 (NTOT*3) /* 3264 */
#define RMINf 0.5f
#define SPANf 5.5f
#define PIf 3.14159265358979323846f

#define OUT_EI 8
#define OUT_FORCE 8200          /* 8 + 8192 */
#define OUT_VIR 34312           /* 8200 + 8*1088*3 */

#define NG2 128                 /* scatter/bwd groups per batch */
#define AT2 (NN/NG2)            /* 8 atoms per fused block */

#define MT 16                   /* atoms per MLP tile */
#define PAD 18                  /* activation LDS leading-dim pad (b64-aligned) */

/* workspace float offsets */
#define WS_S     0
#define WS_DF    (WS_S + 8192*64)
#define WS_FP    (WS_DF + 8192*64)       /* fpart partials: 1024*F3 */
#define WS_STATP (WS_FP + BB*NG2*F3)
#define WS_MUSTD (WS_STATP + 8192*2)
#define WS_VIRP  (WS_MUSTD + 4)          /* 1024*9 */
#define WS_WT    (WS_VIRP + BB*NG2*9)
#define WT0_OFF  0
#define WT1_OFF  16384
#define WT2_OFF  49152

__device__ __forceinline__ float ftanh(float x) {
  const float e = __expf(2.0f*x);
  return 1.0f - 2.0f/(e + 1.0f);
}

/* ---- features via U-factorization + fused weight transpose blocks ---- */
__global__ __launch_bounds__(256) void k_feat(
    const float* __restrict__ rvec, const int* __restrict__ tmap,
    const float* __restrict__ c_param, float* __restrict__ S_ws,
    float* __restrict__ statp,
    const float* __restrict__ W0, const float* __restrict__ W1,
    const float* __restrict__ W2, float* __restrict__ wt)
{
  __shared__ float rv[768];
  __shared__ float c_lds[256];
  __shared__ float prod[256*33];
  __shared__ float part[8*32];
  __shared__ float U[2*32];
  __shared__ float S_lds[64];
  const int tid = threadIdx.x;
  if (blockIdx.x >= BB*NN) {
    const int idx = (blockIdx.x - BB*NN)*256 + tid;
    if (idx < 16384) {
      const int t = idx >> 13, rem = idx & 8191;
      const int j = rem >> 6, f = rem & 63;
      wt[WT0_OFF + idx] = W0[t*8192 + f*128 + j];
    } else if (idx < 49152) {
      const int i = idx - 16384;
      const int t = i >> 14, rem = i & 16383;
      const int j = rem >> 7, f = rem & 127;
      wt[WT1_OFF + i] = W1[t*16384 + f*128 + j];
    } else if (idx < 81920) {
      const int i = idx - 49152;
      const int t = i >> 14, rem = i & 16383;
      const int j = rem >> 7, f = rem & 127;
      wt[WT2_OFF + i] = W2[t*16384 + f*128 + j];
    }
    return;
  }
  const int bn = blockIdx.x;
  const int n = bn & (NN-1);
  const int ti = tmap[n];
  c_lds[tid] = c_param[ti*256 + tid];
  const float* rb = rvec + (size_t)bn*MM*3;
  rv[tid] = rb[tid]; rv[tid+256] = rb[tid+256]; rv[tid+512] = rb[tid+512];
  __syncthreads();
  const int m = tid;
  const float x = rv[3*m], y = rv[3*m+1], z = rv[3*m+2];
  const float r = sqrtf(x*x + y*y + z*z);
  const float inv_r = 1.0f / r;
  const float ux = x*inv_r, uy = y*inv_r, uz = z*inv_r;
  float u = 2.0f*(r - RMINf)/SPANf - 1.0f;
  u = fminf(fmaxf(u, -1.0f), 1.0f);
  const float fc = 0.5f*(__cosf(PIf*(r - RMINf)/SPANf) + 1.0f);
  float T[BETA];
  T[0] = 1.0f; T[1] = u;
  #pragma unroll
  for (int k = 2; k < BETA; ++k) T[k] = 2.0f*u*T[k-1] - T[k-2];
  float* pr = &prod[m*33];
  #pragma unroll
  for (int k = 0; k < BETA; ++k) {
    const float ft = fc*T[k];
    pr[k*4+0] = ft;
    pr[k*4+1] = ft*ux;
    pr[k*4+2] = ft*uy;
    pr[k*4+3] = ft*uz;
  }
  __syncthreads();
  {
    const int c = tid & 31, oct = tid >> 5;
    const int m0 = oct*32;
    float s = 0.f;
    #pragma unroll 8
    for (int i = 0; i < 32; ++i) s += prod[(m0+i)*33 + c];
    part[oct*32 + c] = s;
  }
  __syncthreads();
  if (tid < 64) {
    const int tj = tid >> 5, c = tid & 31;
    U[tid] = part[(tj*4+0)*32+c] + part[(tj*4+1)*32+c]
           + part[(tj*4+2)*32+c] + part[(tj*4+3)*32+c];
  }
  __syncthreads();
  if (tid < 64) {
    const int p = tid >> 2, a = tid & 3;
    float s = 0.f;
    #pragma unroll
    for (int tj = 0; tj < 2; ++tj)
      #pragma unroll
      for (int k = 0; k < 8; ++k)
        s += c_lds[tj*128 + p*8 + k] * U[tj*32 + k*4 + a];
    s *= (1.0f/(float)MM);
    S_lds[tid] = s;
    S_ws[(size_t)bn*64 + tid] = s;
  }
  __syncthreads();
  if (tid < 64) {
    const int p = tid >> 2, q = tid & 3;
    float f = 0.f;
    #pragma unroll
    for (int a = 0; a < 4; ++a) f += S_lds[p*4+a]*S_lds[q*4+a];
    float fs = f, fss = f*f;
    for (int o = 32; o > 0; o >>= 1) { fs += __shfl_down(fs, o); fss += __shfl_down(fss, o); }
    if (tid == 0) { statp[bn*2+0] = fs; statp[bn*2+1] = fss; }
  }
}

/* ---- tiled MLP (round-5 GEMM core, proven no-spill) + in-block stats ---- */
#define GEMM128(WPTR, K, ABUF) \
  for (int kc = 0; kc < (K); kc += 32) { \
    __syncthreads(); \
    { const float4* _s = (const float4*)((WPTR) + kc*128); \
      float4* _d = (float4*)bb; \
      _d[tid] = _s[tid]; _d[tid+256] = _s[tid+256]; \
      _d[tid+512] = _s[tid+512]; _d[tid+768] = _s[tid+768]; } \
    __syncthreads(); \
    _Pragma("unroll 4") \
    for (int k = 0; k < 32; ++k) { \
      const float2 av = *(const float2*)&(ABUF)[(kc+k)*PAD + r0]; \
      const float4 bv = *(const float4*)&bb[k*128 + c0]; \
      acc[0][0] += av.x*bv.x; acc[0][1] += av.x*bv.y; acc[0][2] += av.x*bv.z; acc[0][3] += av.x*bv.w; \
      acc[1][0] += av.y*bv.x; acc[1][1] += av.y*bv.y; acc[1][2] += av.y*bv.z; acc[1][3] += av.y*bv.w; \
    } \
  }

__global__ __launch_bounds__(256, 3) void k_mlp(
    const float* __restrict__ S_ws, const int* __restrict__ tmap,
    const float* __restrict__ statp, const float* __restrict__ wt,
    const float* __restrict__ W0, const float* __restrict__ b0,
    const float* __restrict__ W1, const float* __restrict__ b1,
    const float* __restrict__ W2, const float* __restrict__ b2,
    const float* __restrict__ Wout, const float* __restrict__ bout,
    float* __restrict__ dfeat_ws, float* __restrict__ out)
{
  __shared__ float xb[64*PAD];
  __shared__ float t0b[128*PAD];
  __shared__ float h1b[128*PAD];
  __shared__ float dzb[128*PAD];
  __shared__ float bb[32*128];
  __shared__ float sl[MT*64];
  __shared__ float es[MT];
  __shared__ float srd[8];
  __shared__ float muSd[2];
  const int tb = blockIdx.x;
  const int bn0 = tb*MT;
  const int tid = threadIdx.x;
  const int t = tmap[bn0 & (NN-1)];
  const int rg = tid >> 5, cg = tid & 31;
  const int r0 = rg*2;
  const int c0 = cg*4;
  {
    const float4* src = (const float4*)(S_ws + (size_t)bn0*64);
    ((float4*)sl)[tid] = src[tid];
  }
  {
    float fs = 0.f, fss = 0.f;
    #pragma unroll 4
    for (int i = 0; i < 16; ++i) {
      const int e = i*256 + tid;
      const int b = e >> 9;
      const int n = t*512 + (e & 511);
      const float2 v = *(const float2*)&statp[((size_t)(b*NN + n))*2];
      fs += v.x; fss += v.y;
    }
    for (int o = 32; o > 0; o >>= 1) { fs += __shfl_down(fs, o); fss += __shfl_down(fss, o); }
    if ((tid & 63) == 0) { srd[(tid>>6)*2] = fs; srd[(tid>>6)*2+1] = fss; }
  }
  __syncthreads();
  if (tid == 0) {
    const float S1 = srd[0]+srd[2]+srd[4]+srd[6];
    const float S2 = srd[1]+srd[3]+srd[5]+srd[7];
    const float cnt = 512.0f * (float)BB * (float)NFEAT;
    const float mu = S1/cnt;
    const float var = (S2 - cnt*mu*mu)/(cnt - 1.0f);
    muSd[0] = mu; muSd[1] = sqrtf(fmaxf(var, 1e-20f));
  }
  __syncthreads();
  const float mu = muSd[0];
  const float inv_sd = 1.0f/muSd[1];
  #pragma unroll
  for (int i = 0; i < 4; ++i) {
    const int e = i*256 + tid;
    const int r = e >> 6, f = e & 63;
    const int p = f >> 2, q = f & 3;
    const float* Sr = &sl[r*64];
    float s = 0.f;
    #pragma unroll
    for (int a = 0; a < 4; ++a) s += Sr[p*4+a]*Sr[q*4+a];
    xb[f*PAD + r] = (s - mu)*inv_sd;
  }

  float acc[2][4], dh1r[2][4], wor[4];

  /* L0 */
  {
    const float* bp = b0 + t*HH;
    const float bj0 = bp[c0], bj1 = bp[c0+1], bj2 = bp[c0+2], bj3 = bp[c0+3];
    #pragma unroll
    for (int i = 0; i < 2; ++i) { acc[i][0]=bj0; acc[i][1]=bj1; acc[i][2]=bj2; acc[i][3]=bj3; }
  }
  GEMM128(W0 + (size_t)t*NFEAT*HH, 64, xb);
  __syncthreads();
  #pragma unroll
  for (int i = 0; i < 2; ++i)
    #pragma unroll
    for (int j = 0; j < 4; ++j) t0b[(c0+j)*PAD + r0+i] = ftanh(acc[i][j]);

  /* L1 */
  {
    const float* bp = b1 + t*HH;
    const float bj0 = bp[c0], bj1 = bp[c0+1], bj2 = bp[c0+2], bj3 = bp[c0+3];
    #pragma unroll
    for (int i = 0; i < 2; ++i) { acc[i][0]=bj0; acc[i][1]=bj1; acc[i][2]=bj2; acc[i][3]=bj3; }
  }
  GEMM128(W1 + (size_t)t*HH*HH, 128, t0b);
  __syncthreads();
  #pragma unroll
  for (int i = 0; i < 2; ++i)
    #pragma unroll
    for (int j = 0; j < 4; ++j)
      h1b[(c0+j)*PAD + r0+i] = ftanh(acc[i][j]) + t0b[(c0+j)*PAD + r0+i];

  /* L2 */
  {
    const float* bp = b2 + t*HH;
    const float bj0 = bp[c0], bj1 = bp[c0+1], bj2 = bp[c0+2], bj3 = bp[c0+3];
    #pragma unroll
    for (int i = 0; i < 2; ++i) { acc[i][0]=bj0; acc[i][1]=bj1; acc[i][2]=bj2; acc[i][3]=bj3; }
  }
  GEMM128(W2 + (size_t)t*HH*HH, 128, h1b);
  __syncthreads();

  #pragma unroll
  for (int j = 0; j < 4; ++j) wor[j] = Wout[t*HH + c0 + j];

  /* energy + dz2 */
  {
    float pr0 = 0.f, pr1 = 0.f;
    #pragma unroll
    for (int i = 0; i < 2; ++i)
      #pragma unroll
      for (int j = 0; j < 4; ++j) {
        const float t2 = ftanh(acc[i][j]);
        const float h2 = t2 + h1b[(c0+j)*PAD + r0+i];
        if (i == 0) pr0 += h2*wor[j]; else pr1 += h2*wor[j];
        dzb[(c0+j)*PAD + r0+i] = wor[j]*(1.0f - t2*t2);
      }
    for (int o = 16; o > 0; o >>= 1) {
      pr0 += __shfl_down(pr0, o, 32);
      pr1 += __shfl_down(pr1, o, 32);
    }
    if (cg == 0) { es[r0] = pr0; es[r0+1] = pr1; }
  }
  __syncthreads();
  if (tid < MT) out[OUT_EI + bn0 + tid] = es[tid] + bout[t];

  /* dh1 = wo + dz2 @ W2^T */
  #pragma unroll
  for (int i = 0; i < 2; ++i)
    #pragma unroll
    for (int j = 0; j < 4; ++j) acc[i][j] = wor[j];
  GEMM128(wt + WT2_OFF + (size_t)t*HH*HH, 128, dzb);
  #pragma unroll
  for (int i = 0; i < 2; ++i)
    #pragma unroll
    for (int j = 0; j < 4; ++j) dh1r[i][j] = acc[i][j];
  __syncthreads();
  #pragma unroll
  for (int i = 0; i < 2; ++i)
    #pragma unroll
    for (int j = 0; j < 4; ++j) {
      const float t1 = h1b[(c0+j)*PAD + r0+i] - t0b[(c0+j)*PAD + r0+i];
      dzb[(c0+j)*PAD + r0+i] = dh1r[i][j]*(1.0f - t1*t1);
    }
  /* dh0 = dh1 + dz1 @ W1^T */
  #pragma unroll
  for (int i = 0; i < 2; ++i)
    #pragma unroll
    for (int j = 0; j < 4; ++j) acc[i][j] = dh1r[i][j];
  GEMM128(wt + WT1_OFF + (size_t)t*HH*HH, 128, dzb);
  __syncthreads();
  #pragma unroll
  for (int i = 0; i < 2; ++i)
    #pragma unroll
    for (int j = 0; j < 4; ++j) {
      const float t0 = t0b[(c0+j)*PAD + r0+i];
      dzb[(c0+j)*PAD + r0+i] = acc[i][j]*(1.0f - t0*t0);
    }
  /* dx = dz0 @ W0^T */
  {
    float a2[2][2];
    a2[0][0]=0.f; a2[0][1]=0.f; a2[1][0]=0.f; a2[1][1]=0.f;
    const float* WT0t = wt + WT0_OFF + (size_t)t*HH*NFEAT;
    for (int kc = 0; kc < 128; kc += 32) {
      __syncthreads();
      { const float4* _s = (const float4*)(WT0t + kc*64);
        float4* _d = (float4*)bb;
        _d[tid] = _s[tid]; _d[tid+256] = _s[tid+256]; }
      __syncthreads();
      #pragma unroll 4
      for (int k = 0; k < 32; ++k) {
        const float2 av = *(const float2*)&dzb[(kc+k)*PAD + r0];
        const float2 bv = *(const float2*)&bb[k*64 + cg*2];
        a2[0][0] += av.x*bv.x; a2[0][1] += av.x*bv.y;
        a2[1][0] += av.y*bv.x; a2[1][1] += av.y*bv.y;
      }
    }
    #pragma unroll
    for (int i = 0; i < 2; ++i) {
      float2 v; v.x = a2[i][0]*inv_sd; v.y = a2[i][1]*inv_sd;
      *(float2*)&dfeat_ws[(size_t)(bn0 + r0 + i)*64 + cg*2] = v;
    }
  }
}

/* ---- fused backward pair + scatter kernel ----
   1024 blocks = 8 batches x 128 groups of 8 atoms (4 blocks/CU for TLP).
   Atom loop unrolled x2 for two independent dep chains per wave (ILP). */
__global__ __launch_bounds__(256) void k_bwdsc(
    const float* __restrict__ rvec, const int* __restrict__ nlist,
    const int* __restrict__ tmap, const float* __restrict__ c_param,
    const float* __restrict__ S_ws, const float* __restrict__ dfeat_ws,
    float* __restrict__ fpart_ws, float* __restrict__ virp)
{
  __shared__ float c_lds[256];
  __shared__ float Sb[AT2*64];
  __shared__ float Db[AT2*64];
  __shared__ float dSb[AT2*64];
  __shared__ float Eb[AT2*64];
  __shared__ float fpart[F3];
  __shared__ float wredc[AT2*4*3];
  __shared__ float vred[4*9];
  const int blk = blockIdx.x;          /* b*NG2 + g */
  const int b = blk >> 7;
  const int g = blk & (NG2-1);
  const int n0 = g*AT2;
  const int tid = threadIdx.x;
  const int ti = tmap[n0];             /* type uniform across group (8|512) */
  c_lds[tid] = c_param[ti*256 + tid];
  if (tid < 128) {
    const float4* s4 = (const float4*)(S_ws + ((size_t)b*NN + n0)*64);
    const float4* d4 = (const float4*)(dfeat_ws + ((size_t)b*NN + n0)*64);
    ((float4*)Sb)[tid] = s4[tid];
    ((float4*)Db)[tid] = d4[tid];
  }
  for (int i = tid; i < F3; i += 256) fpart[i] = 0.f;
  __syncthreads();
  /* dS[at][i][a] = sum_q df[i][q] S[q][a] + (i<4) sum_p df[p][i] S[p][a] */
  #pragma unroll
  for (int it = 0; it < 2; ++it) {
    const int idx = it*256 + tid;
    const int at = idx >> 6, f = idx & 63;
    const int i = f >> 2, a = f & 3;
    const float* Sr = &Sb[at*64];
    const float* Dr = &Db[at*64];
    float v = 0.f;
    #pragma unroll
    for (int q = 0; q < 4; ++q) v += Dr[i*4+q]*Sr[q*4+a];
    if (i < 4)
      for (int p = 0; p < 16; ++p) v += Dr[p*4+i]*Sr[p*4+a];
    dSb[idx] = v;
  }
  __syncthreads();
  /* E[at][tj][a][k] = sum_p dS[at][p][a] c[tj][p][k] */
  #pragma unroll
  for (int it = 0; it < 2; ++it) {
    const int idx = it*256 + tid;
    const int at = idx >> 6, rem = idx & 63;
    const int tj = rem >> 5, a = (rem >> 3) & 3, k = rem & 7;
    float e = 0.f;
    #pragma unroll
    for (int p = 0; p < 16; ++p) e += dSb[at*64 + p*4 + a]*c_lds[tj*128 + p*8 + k];
    Eb[idx] = e;
  }
  __syncthreads();

  float vir[9];
  #pragma unroll
  for (int i = 0; i < 9; ++i) vir[i] = 0.f;
  const int wave = tid >> 6, lane = tid & 63;
  const int tjm = tid >> 7;            /* neighbor-type half: m>>7 */
  const float dudr = 2.0f/SPANf;
  const float invM = 1.0f/(float)MM;

  const size_t rowbase = ((size_t)b*NN + n0)*MM;
  float px0, py0, pz0, px1, py1, pz1; int pnl0, pnl1;
  {
    const float* rp0 = rvec + (rowbase + tid)*3;
    const float* rp1 = rvec + (rowbase + MM + tid)*3;
    px0 = rp0[0]; py0 = rp0[1]; pz0 = rp0[2]; pnl0 = nlist[rowbase + tid];
    px1 = rp1[0]; py1 = rp1[1]; pz1 = rp1[2]; pnl1 = nlist[rowbase + MM + tid];
  }
  for (int a0 = 0; a0 < AT2; a0 += 2) {
    const float x0 = px0, y0 = py0, z0 = pz0; const int nl0 = pnl0;
    const float x1 = px1, y1 = py1, z1 = pz1; const int nl1 = pnl1;
    if (a0 + 2 < AT2) {
      const float* rp0 = rvec + (rowbase + (size_t)(a0+2)*MM + tid)*3;
      const float* rp1 = rvec + (rowbase + (size_t)(a0+3)*MM + tid)*3;
      px0 = rp0[0]; py0 = rp0[1]; pz0 = rp0[2];
      pnl0 = nlist[rowbase + (size_t)(a0+2)*MM + tid];
      px1 = rp1[0]; py1 = rp1[1]; pz1 = rp1[2];
      pnl1 = nlist[rowbase + (size_t)(a0+3)*MM + tid];
    }
    const float r_0 = sqrtf(x0*x0 + y0*y0 + z0*z0);
    const float r_1 = sqrtf(x1*x1 + y1*y1 + z1*z1);
    const float ir0 = 1.0f/r_0, ir1 = 1.0f/r_1;
    const float ux0 = x0*ir0, uy0 = y0*ir0, uz0 = z0*ir0;
    const float ux1 = x1*ir1, uy1 = y1*ir1, uz1 = z1*ir1;
    float u0 = 2.0f*(r_0 - RMINf)/SPANf - 1.0f;
    float u1 = 2.0f*(r_1 - RMINf)/SPANf - 1.0f;
    u0 = fminf(fmaxf(u0, -1.0f), 1.0f);
    u1 = fminf(fmaxf(u1, -1.0f), 1.0f);
    float s0a, c0a, s1a, c1a;
    __sincosf(PIf*(r_0 - RMINf)/SPANf, &s0a, &c0a);
    __sincosf(PIf*(r_1 - RMINf)/SPANf, &s1a, &c1a);
    const float fc0 = 0.5f*(c0a + 1.0f), dfc0 = -0.5f*(PIf/SPANf)*s0a;
    const float fc1 = 0.5f*(c1a + 1.0f), dfc1 = -0.5f*(PIf/SPANf)*s1a;
    float T0[BETA], dT0[BETA], T1[BETA], dT1[BETA];
    T0[0]=1.f; T0[1]=u0; dT0[0]=0.f; dT0[1]=1.f;
    T1[0]=1.f; T1[1]=u1; dT1[0]=0.f; dT1[1]=1.f;
    #pragma unroll
    for (int k = 2; k < BETA; ++k) {
      T0[k]  = 2.f*u0*T0[k-1] - T0[k-2];
      dT0[k] = 2.f*T0[k-1] + 2.f*u0*dT0[k-1] - dT0[k-2];
      T1[k]  = 2.f*u1*T1[k-1] - T1[k-2];
      dT1[k] = 2.f*T1[k-1] + 2.f*u1*dT1[k-1] - dT1[k-2];
    }
    const float* Et0 = &Eb[a0*64 + tjm*32];
    const float* Et1 = &Eb[(a0+1)*64 + tjm*32];
    float ta0[4], tda0[4], ta1[4], tda1[4];
    #pragma unroll
    for (int aa = 0; aa < 4; ++aa) {
      float s0 = 0.f, sd0 = 0.f, s1 = 0.f, sd1 = 0.f;
      #pragma unroll
      for (int k = 0; k < 8; ++k) {
        const float e0 = Et0[aa*8 + k];
        const float e1 = Et1[aa*8 + k];
        s0  += T0[k]*e0; sd0 += dT0[k]*e0;
        s1  += T1[k]*e1; sd1 += dT1[k]*e1;
      }
      ta0[aa] = s0; tda0[aa] = sd0;
      ta1[aa] = s1; tda1[aa] = sd1;
    }
    float A0 = dfc0*(ta0[0] + ux0*ta0[1] + uy0*ta0[2] + uz0*ta0[3])
             + fc0*dudr*(tda0[0] + ux0*tda0[1] + uy0*tda0[2] + uz0*tda0[3]);
    float A1 = dfc1*(ta1[0] + ux1*ta1[1] + uy1*ta1[2] + uz1*ta1[3])
             + fc1*dudr*(tda1[0] + ux1*tda1[1] + uy1*tda1[2] + uz1*tda1[3]);
    float q10 = fc0*ta0[1], q20 = fc0*ta0[2], q30 = fc0*ta0[3];
    float q11 = fc1*ta1[1], q21 = fc1*ta1[2], q31 = fc1*ta1[3];
    A0 *= invM; q10 *= invM; q20 *= invM; q30 *= invM;
    A1 *= invM; q11 *= invM; q21 *= invM; q31 *= invM;
    const float qu0 = q10*ux0 + q20*uy0 + q30*uz0;
    const float qu1 = q11*ux1 + q21*uy1 + q31*uz1;
    const float d00 = A0*ux0 + (q10 - qu0*ux0)*ir0;
    const float d01 = A0*uy0 + (q20 - qu0*uy0)*ir0;
    const float d02 = A0*uz0 + (q30 - qu0*uz0)*ir0;
    const float d10 = A1*ux1 + (q11 - qu1*ux1)*ir1;
    const float d11 = A1*uy1 + (q21 - qu1*uy1)*ir1;
    const float d12 = A1*uz1 + (q31 - qu1*uz1)*ir1;
    if (nl0 > 0) {
      const int j = nl0 - 1;
      atomicAdd(&fpart[j*3+0], -d00);
      atomicAdd(&fpart[j*3+1], -d01);
      atomicAdd(&fpart[j*3+2], -d02);
    }
    if (nl1 > 0) {
      const int j = nl1 - 1;
      atomicAdd(&fpart[j*3+0], -d10);
      atomicAdd(&fpart[j*3+1], -d11);
      atomicAdd(&fpart[j*3+2], -d12);
    }
    vir[0] -= x0*d00 + x1*d10; vir[1] -= x0*d01 + x1*d11; vir[2] -= x0*d02 + x1*d12;
    vir[3] -= y0*d00 + y1*d10; vir[4] -= y0*d01 + y1*d11; vir[5] -= y0*d02 + y1*d12;
    vir[6] -= z0*d00 + z1*d10; vir[7] -= z0*d01 + z1*d11; vir[8] -= z0*d02 + z1*d12;
    float r00 = d00, r01 = d01, r02 = d02;
    float r10 = d10, r11 = d11, r12 = d12;
    for (int o = 32; o > 0; o >>= 1) {
      r00 += __shfl_down(r00, o); r01 += __shfl_down(r01, o); r02 += __shfl_down(r02, o);
      r10 += __shfl_down(r10, o); r11 += __shfl_down(r11, o); r12 += __shfl_down(r12, o);
    }
    if (lane == 0) {
      wredc[(a0*4 + wave)*3 + 0] = r00;
      wredc[(a0*4 + wave)*3 + 1] = r01;
      wredc[(a0*4 + wave)*3 + 2] = r02;
      wredc[((a0+1)*4 + wave)*3 + 0] = r10;
      wredc[((a0+1)*4 + wave)*3 + 1] = r11;
      wredc[((a0+1)*4 + wave)*3 + 2] = r12;
    }
  }
  #pragma unroll
  for (int i = 0; i < 9; ++i) {
    float v = vir[i];
    for (int o = 32; o > 0; o >>= 1) v += __shfl_down(v, o);
    if (lane == 0) vred[wave*9 + i] = v;
  }
  __syncthreads();
  if (tid < AT2*3) {
    const int at = tid/3, c = tid - at*3;
    const float v = wredc[(at*4+0)*3+c] + wredc[(at*4+1)*3+c]
                  + wredc[(at*4+2)*3+c] + wredc[(at*4+3)*3+c];
    atomicAdd(&fpart[(n0+at)*3 + c], v);
  }
  if (tid >= 64 && tid < 73) {
    const int i = tid - 64;
    virp[(size_t)blk*9 + i] = vred[i] + vred[9+i] + vred[18+i] + vred[27+i];
  }
  __syncthreads();
  float* dst = fpart_ws + (size_t)blk*F3;
  for (int i = tid; i < F3; i += 256) dst[i] = fpart[i];
}

/* blocks 0..101: force (sum 128 group partials, pure write)
   blocks 102..173: virial per (batch,comp)   blocks 174..181: Etot */
__global__ __launch_bounds__(256) void k_reduce(
    const float* __restrict__ fpart_ws, const float* __restrict__ virp,
    float* __restrict__ out)
{
  __shared__ float red[4];
  const int tid = threadIdx.x;
  const int blk = blockIdx.x;
  if (blk < 102) {
    const int e = blk*256 + tid;       /* e < 26112 == BB*F3 exactly */
    const int b = e / F3;
    const int i = e - b*F3;
    float s = 0.f;
    for (int g = 0; g < NG2; ++g)
      s += fpart_ws[((size_t)(b*NG2 + g))*F3 + i];
    out[OUT_FORCE + e] = s;
    return;
  }
  if (blk < 174) {
    const int vb = blk - 102;
    const int b = vb / 9, c = vb - (vb/9)*9;
    float v = (tid < NG2) ? virp[((size_t)(b*NG2 + tid))*9 + c] : 0.f;
    for (int o = 32; o > 0; o >>= 1) v += __shfl_down(v, o);
    if ((tid & 63) == 0) red[tid >> 6] = v;
    __syncthreads();
    if (tid == 0) out[OUT_VIR + vb] = red[0] + red[1];
    return;
  }
  const int b = blk - 174;
  float v = 0.f;
  #pragma unroll
  for (int k = 0; k < 4; ++k) v += out[OUT_EI + b*NN + k*256 + tid];
  for (int o = 32; o > 0; o >>= 1) v += __shfl_down(v, o);
  if ((tid & 63) == 0) red[tid >> 6] = v;
  __syncthreads();
  if (tid == 0) out[b] = red[0] + red[1] + red[2] + red[3];
}

extern "C" void kernel_launch(void* const* d_in, const int* in_sizes, int n_in,
                              void* d_out, int out_size, void* d_ws, size_t ws_size,
                              hipStream_t stream)
{
  const int*   nlist = (const int*)d_in[0];
  const int*   tmap  = (const int*)d_in[1];
  const float* rvec  = (const float*)d_in[2];
  const float* cpar  = (const float*)d_in[3];
  const float* W0 = (const float*)d_in[4];
  const float* b0 = (const float*)d_in[5];
  const float* W1 = (const float*)d_in[6];
  const float* b1 = (const float*)d_in[7];
  const float* W2 = (const float*)d_in[8];
  const float* b2 = (const float*)d_in[9];
  const float* Wout = (const float*)d_in[10];
  const float* bout = (const float*)d_in[11];
  float* out = (float*)d_out;
  float* ws = (float*)d_ws;
  float* S_ws   = ws + WS_S;
  float* df_ws  = ws + WS_DF;
  float* fpartw = ws + WS_FP;
  float* statp  = ws + WS_STATP;
  float* virp   = ws + WS_VIRP;
  float* wt     = ws + WS_WT;

  k_feat <<<BB*NN + 320, 256, 0, stream>>>(rvec, tmap, cpar, S_ws, statp,
                                           W0, W1, W2, wt);
  k_mlp  <<<(BB*NN)/MT, 256, 0, stream>>>(S_ws, tmap, statp, wt,
                                     W0,b0,W1,b1,W2,b2,Wout,bout, df_ws, out);
  k_bwdsc<<<BB*NG2, 256, 0, stream>>>(rvec, nlist, tmap, cpar, S_ws, df_ws,
                                      fpartw, virp);
  k_reduce<<<182, 256, 0, stream>>>(fpartw, virp, out);
}

// Round 9
// 206.817 us; speedup vs baseline: 4.0589x; 1.0164x over previous
//
#include <hip/hip_runtime.h>
#include <math.h>

#define BB 8
#define NN 1024
#define MM 256
#define BETA 8
#define M1 16
#define NFEAT 64
#define HH 128
#define NTOT 1088   /* N + NGHOST */
#define F3 (NTOT*3) /* 3264 */
#define RMINf 0.5f
#define SPANf 5.5f
#define PIf 3.14159265358979323846f

#define OUT_EI 8
#define OUT_FORCE 8200          /* 8 + 8192 */
#define OUT_VIR 34312           /* 8200 + 8*1088*3 */

#define NG2 128                 /* scatter/bwd groups per batch */
#define AT2 (NN/NG2)            /* 8 atoms per fused block */

#define MT 16                   /* atoms per MLP tile */
#define PAD 18                  /* activation LDS leading-dim pad (b64-aligned) */

/* workspace float offsets */
#define WS_S     0
#define WS_DF    (WS_S + 8192*64)
#define WS_FP    (WS_DF + 8192*64)       /* fpart partials: 1024*F3 */
#define WS_STATP (WS_FP + BB*NG2*F3)
#define WS_MUSTD (WS_STATP + 8192*2)
#define WS_VIRP  (WS_MUSTD + 4)          /* 1024*9 */
#define WS_WT    (WS_VIRP + BB*NG2*9)
#define WT0_OFF  0
#define WT1_OFF  16384
#define WT2_OFF  49152

__device__ __forceinline__ float ftanh(float x) {
  const float e = __expf(2.0f*x);
  return 1.0f - 2.0f/(e + 1.0f);
}

/* ---- features via U-factorization + fused weight transpose blocks ---- */
__global__ __launch_bounds__(256) void k_feat(
    const float* __restrict__ rvec, const int* __restrict__ tmap,
    const float* __restrict__ c_param, float* __restrict__ S_ws,
    float* __restrict__ statp,
    const float* __restrict__ W0, const float* __restrict__ W1,
    const float* __restrict__ W2, float* __restrict__ wt)
{
  __shared__ float rv[768];
  __shared__ float c_lds[256];
  __shared__ float prod[256*33];
  __shared__ float part[8*32];
  __shared__ float U[2*32];
  __shared__ float S_lds[64];
  const int tid = threadIdx.x;
  if (blockIdx.x >= BB*NN) {
    const int idx = (blockIdx.x - BB*NN)*256 + tid;
    if (idx < 16384) {
      const int t = idx >> 13, rem = idx & 8191;
      const int j = rem >> 6, f = rem & 63;
      wt[WT0_OFF + idx] = W0[t*8192 + f*128 + j];
    } else if (idx < 49152) {
      const int i = idx - 16384;
      const int t = i >> 14, rem = i & 16383;
      const int j = rem >> 7, f = rem & 127;
      wt[WT1_OFF + i] = W1[t*16384 + f*128 + j];
    } else if (idx < 81920) {
      const int i = idx - 49152;
      const int t = i >> 14, rem = i & 16383;
      const int j = rem >> 7, f = rem & 127;
      wt[WT2_OFF + i] = W2[t*16384 + f*128 + j];
    }
    return;
  }
  const int bn = blockIdx.x;
  const int n = bn & (NN-1);
  const int ti = tmap[n];
  c_lds[tid] = c_param[ti*256 + tid];
  const float* rb = rvec + (size_t)bn*MM*3;
  rv[tid] = rb[tid]; rv[tid+256] = rb[tid+256]; rv[tid+512] = rb[tid+512];
  __syncthreads();
  const int m = tid;
  const float x = rv[3*m], y = rv[3*m+1], z = rv[3*m+2];
  const float r = sqrtf(x*x + y*y + z*z);
  const float inv_r = 1.0f / r;
  const float ux = x*inv_r, uy = y*inv_r, uz = z*inv_r;
  float u = 2.0f*(r - RMINf)/SPANf - 1.0f;
  u = fminf(fmaxf(u, -1.0f), 1.0f);
  const float fc = 0.5f*(__cosf(PIf*(r - RMINf)/SPANf) + 1.0f);
  float T[BETA];
  T[0] = 1.0f; T[1] = u;
  #pragma unroll
  for (int k = 2; k < BETA; ++k) T[k] = 2.0f*u*T[k-1] - T[k-2];
  float* pr = &prod[m*33];
  #pragma unroll
  for (int k = 0; k < BETA; ++k) {
    const float ft = fc*T[k];
    pr[k*4+0] = ft;
    pr[k*4+1] = ft*ux;
    pr[k*4+2] = ft*uy;
    pr[k*4+3] = ft*uz;
  }
  __syncthreads();
  {
    const int c = tid & 31, oct = tid >> 5;
    const int m0 = oct*32;
    float s = 0.f;
    #pragma unroll 8
    for (int i = 0; i < 32; ++i) s += prod[(m0+i)*33 + c];
    part[oct*32 + c] = s;
  }
  __syncthreads();
  if (tid < 64) {
    const int tj = tid >> 5, c = tid & 31;
    U[tid] = part[(tj*4+0)*32+c] + part[(tj*4+1)*32+c]
           + part[(tj*4+2)*32+c] + part[(tj*4+3)*32+c];
  }
  __syncthreads();
  if (tid < 64) {
    const int p = tid >> 2, a = tid & 3;
    float s = 0.f;
    #pragma unroll
    for (int tj = 0; tj < 2; ++tj)
      #pragma unroll
      for (int k = 0; k < 8; ++k)
        s += c_lds[tj*128 + p*8 + k] * U[tj*32 + k*4 + a];
    s *= (1.0f/(float)MM);
    S_lds[tid] = s;
    S_ws[(size_t)bn*64 + tid] = s;
  }
  __syncthreads();
  if (tid < 64) {
    const int p = tid >> 2, q = tid & 3;
    float f = 0.f;
    #pragma unroll
    for (int a = 0; a < 4; ++a) f += S_lds[p*4+a]*S_lds[q*4+a];
    float fs = f, fss = f*f;
    for (int o = 32; o > 0; o >>= 1) { fs += __shfl_down(fs, o); fss += __shfl_down(fss, o); }
    if (tid == 0) { statp[bn*2+0] = fs; statp[bn*2+1] = fss; }
  }
}

/* ---- tiled MLP (round-5 GEMM core, proven no-spill) + in-block stats ---- */
#define GEMM128(WPTR, K, ABUF) \
  for (int kc = 0; kc < (K); kc += 32) { \
    __syncthreads(); \
    { const float4* _s = (const float4*)((WPTR) + kc*128); \
      float4* _d = (float4*)bb; \
      _d[tid] = _s[tid]; _d[tid+256] = _s[tid+256]; \
      _d[tid+512] = _s[tid+512]; _d[tid+768] = _s[tid+768]; } \
    __syncthreads(); \
    _Pragma("unroll 4") \
    for (int k = 0; k < 32; ++k) { \
      const float2 av = *(const float2*)&(ABUF)[(kc+k)*PAD + r0]; \
      const float4 bv = *(const float4*)&bb[k*128 + c0]; \
      acc[0][0] += av.x*bv.x; acc[0][1] += av.x*bv.y; acc[0][2] += av.x*bv.z; acc[0][3] += av.x*bv.w; \
      acc[1][0] += av.y*bv.x; acc[1][1] += av.y*bv.y; acc[1][2] += av.y*bv.z; acc[1][3] += av.y*bv.w; \
    } \
  }

__global__ __launch_bounds__(256, 3) void k_mlp(
    const float* __restrict__ S_ws, const int* __restrict__ tmap,
    const float* __restrict__ statp, const float* __restrict__ wt,
    const float* __restrict__ W0, const float* __restrict__ b0,
    const float* __restrict__ W1, const float* __restrict__ b1,
    const float* __restrict__ W2, const float* __restrict__ b2,
    const float* __restrict__ Wout, const float* __restrict__ bout,
    float* __restrict__ dfeat_ws, float* __restrict__ out)
{
  __shared__ float xb[64*PAD];
  __shared__ float t0b[128*PAD];
  __shared__ float h1b[128*PAD];
  __shared__ float dzb[128*PAD];
  __shared__ float bb[32*128];
  __shared__ float sl[MT*64];
  __shared__ float es[MT];
  __shared__ float srd[8];
  __shared__ float muSd[2];
  const int tb = blockIdx.x;
  const int bn0 = tb*MT;
  const int tid = threadIdx.x;
  const int t = tmap[bn0 & (NN-1)];
  const int rg = tid >> 5, cg = tid & 31;
  const int r0 = rg*2;
  const int c0 = cg*4;
  {
    const float4* src = (const float4*)(S_ws + (size_t)bn0*64);
    ((float4*)sl)[tid] = src[tid];
  }
  {
    float fs = 0.f, fss = 0.f;
    #pragma unroll 4
    for (int i = 0; i < 16; ++i) {
      const int e = i*256 + tid;
      const int b = e >> 9;
      const int n = t*512 + (e & 511);
      const float2 v = *(const float2*)&statp[((size_t)(b*NN + n))*2];
      fs += v.x; fss += v.y;
    }
    for (int o = 32; o > 0; o >>= 1) { fs += __shfl_down(fs, o); fss += __shfl_down(fss, o); }
    if ((tid & 63) == 0) { srd[(tid>>6)*2] = fs; srd[(tid>>6)*2+1] = fss; }
  }
  __syncthreads();
  if (tid == 0) {
    const float S1 = srd[0]+srd[2]+srd[4]+srd[6];
    const float S2 = srd[1]+srd[3]+srd[5]+srd[7];
    const float cnt = 512.0f * (float)BB * (float)NFEAT;
    const float mu = S1/cnt;
    const float var = (S2 - cnt*mu*mu)/(cnt - 1.0f);
    muSd[0] = mu; muSd[1] = sqrtf(fmaxf(var, 1e-20f));
  }
  __syncthreads();
  const float mu = muSd[0];
  const float inv_sd = 1.0f/muSd[1];
  #pragma unroll
  for (int i = 0; i < 4; ++i) {
    const int e = i*256 + tid;
    const int r = e >> 6, f = e & 63;
    const int p = f >> 2, q = f & 3;
    const float* Sr = &sl[r*64];
    float s = 0.f;
    #pragma unroll
    for (int a = 0; a < 4; ++a) s += Sr[p*4+a]*Sr[q*4+a];
    xb[f*PAD + r] = (s - mu)*inv_sd;
  }

  float acc[2][4], dh1r[2][4], wor[4];

  /* L0 */
  {
    const float* bp = b0 + t*HH;
    const float bj0 = bp[c0], bj1 = bp[c0+1], bj2 = bp[c0+2], bj3 = bp[c0+3];
    #pragma unroll
    for (int i = 0; i < 2; ++i) { acc[i][0]=bj0; acc[i][1]=bj1; acc[i][2]=bj2; acc[i][3]=bj3; }
  }
  GEMM128(W0 + (size_t)t*NFEAT*HH, 64, xb);
  __syncthreads();
  #pragma unroll
  for (int i = 0; i < 2; ++i)
    #pragma unroll
    for (int j = 0; j < 4; ++j) t0b[(c0+j)*PAD + r0+i] = ftanh(acc[i][j]);

  /* L1 */
  {
    const float* bp = b1 + t*HH;
    const float bj0 = bp[c0], bj1 = bp[c0+1], bj2 = bp[c0+2], bj3 = bp[c0+3];
    #pragma unroll
    for (int i = 0; i < 2; ++i) { acc[i][0]=bj0; acc[i][1]=bj1; acc[i][2]=bj2; acc[i][3]=bj3; }
  }
  GEMM128(W1 + (size_t)t*HH*HH, 128, t0b);
  __syncthreads();
  #pragma unroll
  for (int i = 0; i < 2; ++i)
    #pragma unroll
    for (int j = 0; j < 4; ++j)
      h1b[(c0+j)*PAD + r0+i] = ftanh(acc[i][j]) + t0b[(c0+j)*PAD + r0+i];

  /* L2 */
  {
    const float* bp = b2 + t*HH;
    const float bj0 = bp[c0], bj1 = bp[c0+1], bj2 = bp[c0+2], bj3 = bp[c0+3];
    #pragma unroll
    for (int i = 0; i < 2; ++i) { acc[i][0]=bj0; acc[i][1]=bj1; acc[i][2]=bj2; acc[i][3]=bj3; }
  }
  GEMM128(W2 + (size_t)t*HH*HH, 128, h1b);
  __syncthreads();

  #pragma unroll
  for (int j = 0; j < 4; ++j) wor[j] = Wout[t*HH + c0 + j];

  /* energy + dz2 */
  {
    float pr0 = 0.f, pr1 = 0.f;
    #pragma unroll
    for (int i = 0; i < 2; ++i)
      #pragma unroll
      for (int j = 0; j < 4; ++j) {
        const float t2 = ftanh(acc[i][j]);
        const float h2 = t2 + h1b[(c0+j)*PAD + r0+i];
        if (i == 0) pr0 += h2*wor[j]; else pr1 += h2*wor[j];
        dzb[(c0+j)*PAD + r0+i] = wor[j]*(1.0f - t2*t2);
      }
    for (int o = 16; o > 0; o >>= 1) {
      pr0 += __shfl_down(pr0, o, 32);
      pr1 += __shfl_down(pr1, o, 32);
    }
    if (cg == 0) { es[r0] = pr0; es[r0+1] = pr1; }
  }
  __syncthreads();
  if (tid < MT) out[OUT_EI + bn0 + tid] = es[tid] + bout[t];

  /* dh1 = wo + dz2 @ W2^T */
  #pragma unroll
  for (int i = 0; i < 2; ++i)
    #pragma unroll
    for (int j = 0; j < 4; ++j) acc[i][j] = wor[j];
  GEMM128(wt + WT2_OFF + (size_t)t*HH*HH, 128, dzb);
  #pragma unroll
  for (int i = 0; i < 2; ++i)
    #pragma unroll
    for (int j = 0; j < 4; ++j) dh1r[i][j] = acc[i][j];
  __syncthreads();
  #pragma unroll
  for (int i = 0; i < 2; ++i)
    #pragma unroll
    for (int j = 0; j < 4; ++j) {
      const float t1 = h1b[(c0+j)*PAD + r0+i] - t0b[(c0+j)*PAD + r0+i];
      dzb[(c0+j)*PAD + r0+i] = dh1r[i][j]*(1.0f - t1*t1);
    }
  /* dh0 = dh1 + dz1 @ W1^T */
  #pragma unroll
  for (int i = 0; i < 2; ++i)
    #pragma unroll
    for (int j = 0; j < 4; ++j) acc[i][j] = dh1r[i][j];
  GEMM128(wt + WT1_OFF + (size_t)t*HH*HH, 128, dzb);
  __syncthreads();
  #pragma unroll
  for (int i = 0; i < 2; ++i)
    #pragma unroll
    for (int j = 0; j < 4; ++j) {
      const float t0 = t0b[(c0+j)*PAD + r0+i];
      dzb[(c0+j)*PAD + r0+i] = acc[i][j]*(1.0f - t0*t0);
    }
  /* dx = dz0 @ W0^T */
  {
    float a2[2][2];
    a2[0][0]=0.f; a2[0][1]=0.f; a2[1][0]=0.f; a2[1][1]=0.f;
    const float* WT0t = wt + WT0_OFF + (size_t)t*HH*NFEAT;
    for (int kc = 0; kc < 128; kc += 32) {
      __syncthreads();
      { const float4* _s = (const float4*)(WT0t + kc*64);
        float4* _d = (float4*)bb;
        _d[tid] = _s[tid]; _d[tid+256] = _s[tid+256]; }
      __syncthreads();
      #pragma unroll 4
      for (int k = 0; k < 32; ++k) {
        const float2 av = *(const float2*)&dzb[(kc+k)*PAD + r0];
        const float2 bv = *(const float2*)&bb[k*64 + cg*2];
        a2[0][0] += av.x*bv.x; a2[0][1] += av.x*bv.y;
        a2[1][0] += av.y*bv.x; a2[1][1] += av.y*bv.y;
      }
    }
    #pragma unroll
    for (int i = 0; i < 2; ++i) {
      float2 v; v.x = a2[i][0]*inv_sd; v.y = a2[i][1]*inv_sd;
      *(float2*)&dfeat_ws[(size_t)(bn0 + r0 + i)*64 + cg*2] = v;
    }
  }
}

/* ---- fused backward pair + scatter kernel, wave-owns-atom ----
   1024 blocks = 8 batches x 128 groups of 8 atoms; wave w owns atoms 2w,2w+1.
   E coefficients (32/atom/half) load once into registers via ds_read_b128 and
   are reused across 128 pairs; dual-chunk ILP; center force reduced in regs.
   Cuts DS-pipe ops/wave ~4x vs round-8 (256 b32 E reads + 144 shfl -> 32 b128
   + 36 shfl). */
__global__ __launch_bounds__(256) void k_bwdsc(
    const float* __restrict__ rvec, const int* __restrict__ nlist,
    const int* __restrict__ tmap, const float* __restrict__ c_param,
    const float* __restrict__ S_ws, const float* __restrict__ dfeat_ws,
    float* __restrict__ fpart_ws, float* __restrict__ virp)
{
  __shared__ float c_lds[256];
  __shared__ float Sb[AT2*64];
  __shared__ float Db[AT2*64];
  __shared__ float dSb[AT2*64];
  __shared__ float Eb[AT2*64];
  __shared__ float fpart[F3];
  __shared__ float vred[4*9];
  const int blk = blockIdx.x;          /* b*NG2 + g */
  const int b = blk >> 7;
  const int g = blk & (NG2-1);
  const int n0 = g*AT2;
  const int tid = threadIdx.x;
  const int wave = tid >> 6, lane = tid & 63;
  const int ti = tmap[n0];             /* type uniform across group (8|512) */
  c_lds[tid] = c_param[ti*256 + tid];
  if (tid < 128) {
    const float4* s4 = (const float4*)(S_ws + ((size_t)b*NN + n0)*64);
    const float4* d4 = (const float4*)(dfeat_ws + ((size_t)b*NN + n0)*64);
    ((float4*)Sb)[tid] = s4[tid];
    ((float4*)Db)[tid] = d4[tid];
  }
  {
    const float4 z4 = {0.f, 0.f, 0.f, 0.f};
    for (int i = tid; i < F3/4; i += 256) ((float4*)fpart)[i] = z4;
  }
  __syncthreads();
  /* dS[at][i][a] = sum_q df[i][q] S[q][a] + (i<4) sum_p df[p][i] S[p][a] */
  #pragma unroll
  for (int it = 0; it < 2; ++it) {
    const int idx = it*256 + tid;
    const int at = idx >> 6, f = idx & 63;
    const int i = f >> 2, a = f & 3;
    const float* Sr = &Sb[at*64];
    const float* Dr = &Db[at*64];
    float v = 0.f;
    #pragma unroll
    for (int q = 0; q < 4; ++q) v += Dr[i*4+q]*Sr[q*4+a];
    if (i < 4)
      for (int p = 0; p < 16; ++p) v += Dr[p*4+i]*Sr[p*4+a];
    dSb[idx] = v;
  }
  __syncthreads();
  /* E[at][tj][a][k] = sum_p dS[at][p][a] c[tj][p][k] */
  #pragma unroll
  for (int it = 0; it < 2; ++it) {
    const int idx = it*256 + tid;
    const int at = idx >> 6, rem = idx & 63;
    const int tj = rem >> 5, a = (rem >> 3) & 3, k = rem & 7;
    float e = 0.f;
    #pragma unroll
    for (int p = 0; p < 16; ++p) e += dSb[at*64 + p*4 + a]*c_lds[tj*128 + p*8 + k];
    Eb[idx] = e;
  }
  __syncthreads();

  float vir[9];
  #pragma unroll
  for (int i = 0; i < 9; ++i) vir[i] = 0.f;
  const float dudr = 2.0f/SPANf;
  const float invM = 1.0f/(float)MM;

  for (int w_at = 0; w_at < 2; ++w_at) {
    const int at = wave*2 + w_at;
    const size_t rowb = ((size_t)b*NN + n0 + at)*(size_t)MM;
    float cf0 = 0.f, cf1 = 0.f, cf2 = 0.f;
    #pragma unroll
    for (int half = 0; half < 2; ++half) {
      /* E coefficients for this atom's tj-half: 8 x b128, reused 128 pairs */
      float Er[32];
      {
        const float4* Ep = (const float4*)&Eb[at*64 + half*32];
        #pragma unroll
        for (int q = 0; q < 8; ++q) {
          const float4 v = Ep[q];
          Er[q*4+0] = v.x; Er[q*4+1] = v.y; Er[q*4+2] = v.z; Er[q*4+3] = v.w;
        }
      }
      const int m0 = half*128 + lane;
      const int m1 = m0 + 64;
      const float* rp0 = rvec + (rowb + m0)*3;
      const float* rp1 = rvec + (rowb + m1)*3;
      const float x0 = rp0[0], y0 = rp0[1], z0 = rp0[2];
      const float x1 = rp1[0], y1 = rp1[1], z1 = rp1[2];
      const int nl0 = nlist[rowb + m0];
      const int nl1 = nlist[rowb + m1];
      const float r_0 = sqrtf(x0*x0 + y0*y0 + z0*z0);
      const float r_1 = sqrtf(x1*x1 + y1*y1 + z1*z1);
      const float ir0 = 1.0f/r_0, ir1 = 1.0f/r_1;
      const float ux0 = x0*ir0, uy0 = y0*ir0, uz0 = z0*ir0;
      const float ux1 = x1*ir1, uy1 = y1*ir1, uz1 = z1*ir1;
      float u0 = 2.0f*(r_0 - RMINf)/SPANf - 1.0f;
      float u1 = 2.0f*(r_1 - RMINf)/SPANf - 1.0f;
      u0 = fminf(fmaxf(u0, -1.0f), 1.0f);
      u1 = fminf(fmaxf(u1, -1.0f), 1.0f);
      float s0a, c0a, s1a, c1a;
      __sincosf(PIf*(r_0 - RMINf)/SPANf, &s0a, &c0a);
      __sincosf(PIf*(r_1 - RMINf)/SPANf, &s1a, &c1a);
      const float fc0 = 0.5f*(c0a + 1.0f), dfc0 = -0.5f*(PIf/SPANf)*s0a;
      const float fc1 = 0.5f*(c1a + 1.0f), dfc1 = -0.5f*(PIf/SPANf)*s1a;
      float T0[BETA], dT0[BETA], T1[BETA], dT1[BETA];
      T0[0]=1.f; T0[1]=u0; dT0[0]=0.f; dT0[1]=1.f;
      T1[0]=1.f; T1[1]=u1; dT1[0]=0.f; dT1[1]=1.f;
      #pragma unroll
      for (int k = 2; k < BETA; ++k) {
        T0[k]  = 2.f*u0*T0[k-1] - T0[k-2];
        dT0[k] = 2.f*T0[k-1] + 2.f*u0*dT0[k-1] - dT0[k-2];
        T1[k]  = 2.f*u1*T1[k-1] - T1[k-2];
        dT1[k] = 2.f*T1[k-1] + 2.f*u1*dT1[k-1] - dT1[k-2];
      }
      float ta0[4], tda0[4], ta1[4], tda1[4];
      #pragma unroll
      for (int aa = 0; aa < 4; ++aa) {
        float s0 = 0.f, sd0 = 0.f, s1 = 0.f, sd1 = 0.f;
        #pragma unroll
        for (int k = 0; k < 8; ++k) {
          const float e = Er[aa*8 + k];
          s0  += T0[k]*e; sd0 += dT0[k]*e;
          s1  += T1[k]*e; sd1 += dT1[k]*e;
        }
        ta0[aa] = s0; tda0[aa] = sd0;
        ta1[aa] = s1; tda1[aa] = sd1;
      }
      float A0 = dfc0*(ta0[0] + ux0*ta0[1] + uy0*ta0[2] + uz0*ta0[3])
               + fc0*dudr*(tda0[0] + ux0*tda0[1] + uy0*tda0[2] + uz0*tda0[3]);
      float A1 = dfc1*(ta1[0] + ux1*ta1[1] + uy1*ta1[2] + uz1*ta1[3])
               + fc1*dudr*(tda1[0] + ux1*tda1[1] + uy1*tda1[2] + uz1*tda1[3]);
      float q10 = fc0*ta0[1], q20 = fc0*ta0[2], q30 = fc0*ta0[3];
      float q11 = fc1*ta1[1], q21 = fc1*ta1[2], q31 = fc1*ta1[3];
      A0 *= invM; q10 *= invM; q20 *= invM; q30 *= invM;
      A1 *= invM; q11 *= invM; q21 *= invM; q31 *= invM;
      const float qu0 = q10*ux0 + q20*uy0 + q30*uz0;
      const float qu1 = q11*ux1 + q21*uy1 + q31*uz1;
      const float d00 = A0*ux0 + (q10 - qu0*ux0)*ir0;
      const float d01 = A0*uy0 + (q20 - qu0*uy0)*ir0;
      const float d02 = A0*uz0 + (q30 - qu0*uz0)*ir0;
      const float d10 = A1*ux1 + (q11 - qu1*ux1)*ir1;
      const float d11 = A1*uy1 + (q21 - qu1*uy1)*ir1;
      const float d12 = A1*uz1 + (q31 - qu1*uz1)*ir1;
      if (nl0 > 0) {
        const int j = nl0 - 1;
        atomicAdd(&fpart[j*3+0], -d00);
        atomicAdd(&fpart[j*3+1], -d01);
        atomicAdd(&fpart[j*3+2], -d02);
      }
      if (nl1 > 0) {
        const int j = nl1 - 1;
        atomicAdd(&fpart[j*3+0], -d10);
        atomicAdd(&fpart[j*3+1], -d11);
        atomicAdd(&fpart[j*3+2], -d12);
      }
      vir[0] -= x0*d00 + x1*d10; vir[1] -= x0*d01 + x1*d11; vir[2] -= x0*d02 + x1*d12;
      vir[3] -= y0*d00 + y1*d10; vir[4] -= y0*d01 + y1*d11; vir[5] -= y0*d02 + y1*d12;
      vir[6] -= z0*d00 + z1*d10; vir[7] -= z0*d01 + z1*d11; vir[8] -= z0*d02 + z1*d12;
      cf0 += d00 + d10; cf1 += d01 + d11; cf2 += d02 + d12;
    }
    for (int o = 32; o > 0; o >>= 1) {
      cf0 += __shfl_down(cf0, o);
      cf1 += __shfl_down(cf1, o);
      cf2 += __shfl_down(cf2, o);
    }
    if (lane == 0) {
      atomicAdd(&fpart[(n0+at)*3+0], cf0);
      atomicAdd(&fpart[(n0+at)*3+1], cf1);
      atomicAdd(&fpart[(n0+at)*3+2], cf2);
    }
  }
  #pragma unroll
  for (int i = 0; i < 9; ++i) {
    float v = vir[i];
    for (int o = 32; o > 0; o >>= 1) v += __shfl_down(v, o);
    if (lane == 0) vred[wave*9 + i] = v;
  }
  __syncthreads();
  if (tid >= 64 && tid < 73) {
    const int i = tid - 64;
    virp[(size_t)blk*9 + i] = vred[i] + vred[9+i] + vred[18+i] + vred[27+i];
  }
  {
    float* dst = fpart_ws + (size_t)blk*F3;
    for (int i = tid; i < F3/4; i += 256)
      ((float4*)dst)[i] = ((float4*)fpart)[i];
  }
}

/* blocks 0..101: force (sum 128 group partials, pure write)
   blocks 102..173: virial per (batch,comp)   blocks 174..181: Etot */
__global__ __launch_bounds__(256) void k_reduce(
    const float* __restrict__ fpart_ws, const float* __restrict__ virp,
    float* __restrict__ out)
{
  __shared__ float red[4];
  const int tid = threadIdx.x;
  const int blk = blockIdx.x;
  if (blk < 102) {
    const int e = blk*256 + tid;       /* e < 26112 == BB*F3 exactly */
    const int b = e / F3;
    const int i = e - b*F3;
    float s = 0.f;
    for (int g = 0; g < NG2; ++g)
      s += fpart_ws[((size_t)(b*NG2 + g))*F3 + i];
    out[OUT_FORCE + e] = s;
    return;
  }
  if (blk < 174) {
    const int vb = blk - 102;
    const int b = vb / 9, c = vb - (vb/9)*9;
    float v = (tid < NG2) ? virp[((size_t)(b*NG2 + tid))*9 + c] : 0.f;
    for (int o = 32; o > 0; o >>= 1) v += __shfl_down(v, o);
    if ((tid & 63) == 0) red[tid >> 6] = v;
    __syncthreads();
    if (tid == 0) out[OUT_VIR + vb] = red[0] + red[1];
    return;
  }
  const int b = blk - 174;
  float v = 0.f;
  #pragma unroll
  for (int k = 0; k < 4; ++k) v += out[OUT_EI + b*NN + k*256 + tid];
  for (int o = 32; o > 0; o >>= 1) v += __shfl_down(v, o);
  if ((tid & 63) == 0) red[tid >> 6] = v;
  __syncthreads();
  if (tid == 0) out[b] = red[0] + red[1] + red[2] + red[3];
}

extern "C" void kernel_launch(void* const* d_in, const int* in_sizes, int n_in,
                              void* d_out, int out_size, void* d_ws, size_t ws_size,
                              hipStream_t stream)
{
  const int*   nlist = (const int*)d_in[0];
  const int*   tmap  = (const int*)d_in[1];
  const float* rvec  = (const float*)d_in[2];
  const float* cpar  = (const float*)d_in[3];
  const float* W0 = (const float*)d_in[4];
  const float* b0 = (const float*)d_in[5];
  const float* W1 = (const float*)d_in[6];
  const float* b1 = (const float*)d_in[7];
  const float* W2 = (const float*)d_in[8];
  const float* b2 = (const float*)d_in[9];
  const float* Wout = (const float*)d_in[10];
  const float* bout = (const float*)d_in[11];
  float* out = (float*)d_out;
  float* ws = (float*)d_ws;
  float* S_ws   = ws + WS_S;
  float* df_ws  = ws + WS_DF;
  float* fpartw = ws + WS_FP;
  float* statp  = ws + WS_STATP;
  float* virp   = ws + WS_VIRP;
  float* wt     = ws + WS_WT;

  k_feat <<<BB*NN + 320, 256, 0, stream>>>(rvec, tmap, cpar, S_ws, statp,
                                           W0, W1, W2, wt);
  k_mlp  <<<(BB*NN)/MT, 256, 0, stream>>>(S_ws, tmap, statp, wt,
                                     W0,b0,W1,b1,W2,b2,Wout,bout, df_ws, out);
  k_bwdsc<<<BB*NG2, 256, 0, stream>>>(rvec, nlist, tmap, cpar, S_ws, df_ws,
                                      fpartw, virp);
  k_reduce<<<182, 256, 0, stream>>>(fpartw, virp, out);
}